// Round 4
// baseline (25765.515 us; speedup 1.0000x reference)
//
#include <hip/hip_runtime.h>

// VQ quantizer: N=65536 rows (D=64) vs K=4096 codes. d_out = FLOAT32
// [x_quantized N*D][indices N][loss 1].
//
// Round-4: two-phase MFMA pruning.
//  - exact semantics (ref = f32 numpy port): score_e = fl(fl(sx+sc) - fl(2*dot)),
//    dot = sequential-d f32 FMA chain (verified PASS in round 3).
//  - phase 1: bf16 MFMA approx scores. |score_a - score_e| <= ~7.5e-4 worst case
//    (|c|<=2.5e-4, |x|<=6, single-bf16 product error 2^-8|x||c| per element).
//    Sweep A: per-row approx min. Sweep B: candidates with s_a <= min_a + 2e-3
//    (provable superset of exact winner + ties). Resolve: exact rescore of
//    candidates (avg ~9/row), lex (score, idx) min. Overflow -> fallback kernel.

#define D  64
#define NTILES 256   // K/16

typedef unsigned short u16;
typedef short bf16x8 __attribute__((ext_vector_type(8)));
typedef float f32x4  __attribute__((ext_vector_type(4)));

__device__ __forceinline__ u16 f32_to_bf16_raw(float f) {
    union { float f; unsigned u; } v; v.f = f;
    unsigned u = v.u;
    u += 0x7FFFu + ((u >> 16) & 1u);   // RNE
    return (u16)(u >> 16);
}

// ---------- numpy-exact row sum of squares (pairwise n=64 pattern) ----------
__device__ __forceinline__ float np_pairwise_sumsq_64(const float* p) {
    float r[8];
    #pragma unroll
    for (int j = 0; j < 8; ++j) r[j] = __fmul_rn(p[j], p[j]);
    #pragma unroll
    for (int i = 8; i < 64; i += 8) {
        #pragma unroll
        for (int j = 0; j < 8; ++j)
            r[j] = __fadd_rn(r[j], __fmul_rn(p[i + j], p[i + j]));
    }
    float t0 = __fadd_rn(r[0], r[1]);
    float t1 = __fadd_rn(r[2], r[3]);
    float t2 = __fadd_rn(r[4], r[5]);
    float t3 = __fadd_rn(r[6], r[7]);
    return __fadd_rn(__fadd_rn(t0, t1), __fadd_rn(t2, t3));
}

__global__ __launch_bounds__(256) void rowsumsq_kernel(const float* __restrict__ a,
                                                       float* __restrict__ out, int nrows) {
    int r = blockIdx.x * 256 + threadIdx.x;
    if (r >= nrows) return;
    float buf[64];
    const float4* p = (const float4*)(a + (size_t)r * D);
    #pragma unroll
    for (int i = 0; i < 16; ++i) {
        float4 v = p[i];
        buf[4*i] = v.x; buf[4*i+1] = v.y; buf[4*i+2] = v.z; buf[4*i+3] = v.w;
    }
    out[r] = np_pairwise_sumsq_64(buf);
}

// ---------- pack codebook into B-fragment layout (bf16), 512 KB ----------
// frag element j of lane l (tile t, kstep ks): code = t*16+(l&15),
// d = ks*32 + (l>>4)*4 + (j&3) + 16*(j>>2).  Same rule used for A-frags (x),
// so any common error in the k-mapping cancels in the dot product.
__global__ __launch_bounds__(128) void pack_cb(const float* __restrict__ cb,
                                               bf16x8* __restrict__ cbf) {
    int t = blockIdx.x;
    int ks = threadIdx.x >> 6;
    int lane = threadIdx.x & 63;
    int code = t * 16 + (lane & 15);
    int g = lane >> 4;
    bf16x8 v;
    #pragma unroll
    for (int j = 0; j < 8; ++j) {
        int d = ks * 32 + g * 4 + (j & 3) + 16 * (j >> 2);
        v[j] = (short)f32_to_bf16_raw(cb[(size_t)code * D + d]);
    }
    cbf[(t * 2 + ks) * 64 + lane] = v;
}

// ---------- phase 1: MFMA sweeps + exact resolve ----------
__device__ __forceinline__ f32x4 tile_dot(bf16x8 a0, bf16x8 a1,
                                          const bf16x8* __restrict__ cbl, int t) {
    bf16x8 b0 = cbl[t * 128];
    bf16x8 b1 = cbl[t * 128 + 64];
    f32x4 acc = {0.f, 0.f, 0.f, 0.f};
    acc = __builtin_amdgcn_mfma_f32_16x16x32_bf16(a0, b0, acc, 0, 0, 0);
    acc = __builtin_amdgcn_mfma_f32_16x16x32_bf16(a1, b1, acc, 0, 0, 0);
    return acc;
}

#define MARGIN 2.0e-3f
#define CAP 32

__global__ __launch_bounds__(256) void phase1_kernel(
    const float* __restrict__ x, const float* __restrict__ cb,
    const float* __restrict__ sx, const float* __restrict__ sc,
    const bf16x8* __restrict__ cbf,
    int* __restrict__ idxbuf, int* __restrict__ ovf_cnt, int* __restrict__ ovf_rows)
{
    __shared__ float xs[64][68];     // f32 x tile (also used by exact resolve)
    __shared__ float sxl[64];
    __shared__ float scl[4096];
    __shared__ int   cnt[64];
    __shared__ int   list[64][CAP];
    __shared__ float rbv[64][4];
    __shared__ int   rbi[64][4];

    const int tid = threadIdx.x;
    const int n0  = blockIdx.x * 64;
    const int lane = tid & 63, w = tid >> 6;
    const int r = lane & 15, g = lane >> 4;

    #pragma unroll
    for (int j = 0; j < 16; ++j) {                 // coalesced f32 x stage
        int e = tid + j * 256; int row = e >> 6, d = e & 63;
        xs[row][d] = x[(size_t)(n0 + row) * D + d];
    }
    if (tid < 64) { sxl[tid] = sx[n0 + tid]; cnt[tid] = 0; }
    for (int j = tid; j < 4096; j += 256) scl[j] = sc[j];
    __syncthreads();

    // A fragments: row = w*16 + (l&15), k-map identical to pack_cb
    bf16x8 a0, a1;
    #pragma unroll
    for (int j = 0; j < 8; ++j) {
        int d0 = g * 4 + (j & 3) + 16 * (j >> 2);
        a0[j] = (short)f32_to_bf16_raw(xs[w * 16 + r][d0]);
        a1[j] = (short)f32_to_bf16_raw(xs[w * 16 + r][32 + d0]);
    }
    float sxr[4];
    #pragma unroll
    for (int q = 0; q < 4; ++q) sxr[q] = sxl[w * 16 + g * 4 + q];

    const bf16x8* cbl = cbf + lane;

    // ---- sweep A: per-row approx minima ----
    float bv[4] = {3.4e38f, 3.4e38f, 3.4e38f, 3.4e38f};
    #pragma unroll 2
    for (int t = 0; t < NTILES; ++t) {
        f32x4 acc = tile_dot(a0, a1, cbl, t);
        float sck = scl[t * 16 + r];
        #pragma unroll
        for (int q = 0; q < 4; ++q) {
            float tt = __fadd_rn(sxr[q], sck);
            float u  = __fmul_rn(2.0f, acc[q]);
            float s  = __fsub_rn(tt, u);
            bv[q] = fminf(bv[q], s);
        }
    }
    #pragma unroll
    for (int m = 1; m < 16; m <<= 1) {             // reduce over the 16 codes/lane-group
        #pragma unroll
        for (int q = 0; q < 4; ++q) bv[q] = fminf(bv[q], __shfl_xor(bv[q], m, 64));
    }
    float thr[4];
    #pragma unroll
    for (int q = 0; q < 4; ++q) thr[q] = bv[q] + MARGIN;

    // ---- sweep B: collect candidate codes (bit-identical score recompute) ----
    #pragma unroll 2
    for (int t = 0; t < NTILES; ++t) {
        f32x4 acc = tile_dot(a0, a1, cbl, t);
        float sck = scl[t * 16 + r];
        float s4[4]; bool h[4]; bool any = false;
        #pragma unroll
        for (int q = 0; q < 4; ++q) {
            float tt = __fadd_rn(sxr[q], sck);
            float u  = __fmul_rn(2.0f, acc[q]);
            s4[q] = __fsub_rn(tt, u);
            h[q] = (s4[q] <= thr[q]);
            any |= h[q];
        }
        if (__any(any)) {
            #pragma unroll
            for (int q = 0; q < 4; ++q) if (h[q]) {
                int row = w * 16 + g * 4 + q;
                int slot = atomicAdd(&cnt[row], 1);
                if (slot < CAP) list[row][slot] = t * 16 + r;
            }
        }
    }
    __syncthreads();

    // ---- resolve: exact sequential-FMA rescore of candidates, 4 threads/row ----
    {
        int row = tid >> 2, su = tid & 3;
        int c = cnt[row]; int cc = c < CAP ? c : CAP;
        float bvv = 3.4e38f; int bii = 0x7fffffff;
        for (int i = su; i < cc; i += 4) {
            int k = list[row][i];
            const float* crow = cb + (size_t)k * D;
            float acc = 0.f;
            #pragma unroll
            for (int d = 0; d < 64; ++d) acc = __fmaf_rn(xs[row][d], crow[d], acc);
            float tt = __fadd_rn(sxl[row], scl[k]);
            float u  = __fmul_rn(2.0f, acc);
            float s  = __fsub_rn(tt, u);
            if (s < bvv || (s == bvv && k < bii)) { bvv = s; bii = k; }
        }
        rbv[row][su] = bvv; rbi[row][su] = bii;
    }
    __syncthreads();
    if (tid < 64) {
        int row = tid;
        float bvv = rbv[row][0]; int bii = rbi[row][0];
        #pragma unroll
        for (int i = 1; i < 4; ++i) {
            float v = rbv[row][i]; int k = rbi[row][i];
            if (v < bvv || (v == bvv && k < bii)) { bvv = v; bii = k; }
        }
        if (cnt[row] > CAP) {                       // rare: full rescan fallback
            int slot = atomicAdd(ovf_cnt, 1);
            ovf_rows[slot] = n0 + row;
        }
        idxbuf[n0 + row] = bii;                     // overwritten by fallback if ovf
    }
}

// ---------- fallback: exact full-K argmin for overflowed rows ----------
__global__ __launch_bounds__(256) void fallback_kernel(
    const float* __restrict__ x, const float* __restrict__ cb,
    const float* __restrict__ sx, const float* __restrict__ sc,
    const int* __restrict__ ovf_cnt, const int* __restrict__ ovf_rows,
    int* __restrict__ idxbuf)
{
    __shared__ float rv[256]; __shared__ int ri[256];
    __shared__ float xrow[64];
    int count = *ovf_cnt;
    for (int i = blockIdx.x; i < count; i += gridDim.x) {
        int n = ovf_rows[i];
        if (threadIdx.x < 64) xrow[threadIdx.x] = x[(size_t)n * D + threadIdx.x];
        __syncthreads();
        float sxn = sx[n];
        float bvv = 3.4e38f; int bii = 0x7fffffff;
        for (int k = threadIdx.x; k < 4096; k += 256) {
            const float* crow = cb + (size_t)k * D;
            float acc = 0.f;
            #pragma unroll
            for (int d = 0; d < 64; ++d) acc = __fmaf_rn(xrow[d], crow[d], acc);
            float tt = __fadd_rn(sxn, sc[k]);
            float u  = __fmul_rn(2.0f, acc);
            float s  = __fsub_rn(tt, u);
            if (s < bvv || (s == bvv && k < bii)) { bvv = s; bii = k; }
        }
        rv[threadIdx.x] = bvv; ri[threadIdx.x] = bii;
        __syncthreads();
        for (int st = 128; st > 0; st >>= 1) {
            if ((int)threadIdx.x < st) {
                float v2 = rv[threadIdx.x + st]; int k2 = ri[threadIdx.x + st];
                if (v2 < rv[threadIdx.x] || (v2 == rv[threadIdx.x] && k2 < ri[threadIdx.x])) {
                    rv[threadIdx.x] = v2; ri[threadIdx.x] = k2;
                }
            }
            __syncthreads();
        }
        if (threadIdx.x == 0) idxbuf[n] = ri[0];
        __syncthreads();
    }
}

// ---------- finalize + loss (unchanged from round 3, PASS-verified) ----------
__global__ __launch_bounds__(256) void finalize_rows(
    const float* __restrict__ x, const float* __restrict__ cb,
    const int* __restrict__ idxbuf,
    float* __restrict__ out_q, float* __restrict__ out_i,
    double* __restrict__ partials, int N)
{
    __shared__ double wsum[4];
    int wid = threadIdx.x >> 6, lane = threadIdx.x & 63;
    int n = blockIdx.x * 4 + wid;

    int idx = idxbuf[n];
    float q  = cb[(size_t)idx * D + lane];
    float xv = x[(size_t)n * D + lane];
    out_q[(size_t)n * D + lane] = q;

    double diff = (double)xv - (double)q;
    double s = diff * diff;
    #pragma unroll
    for (int off = 32; off > 0; off >>= 1) s += __shfl_down(s, off, 64);
    if (lane == 0) { wsum[wid] = s; out_i[n] = (float)idx; }
    __syncthreads();
    if (threadIdx.x == 0) partials[blockIdx.x] = (wsum[0] + wsum[1]) + (wsum[2] + wsum[3]);
}

__global__ __launch_bounds__(256) void loss_kernel(const double* __restrict__ partials,
                                                   int nP, float* __restrict__ out_loss,
                                                   double invND)
{
    __shared__ double red[256];
    double s = 0.0;
    for (int i = threadIdx.x; i < nP; i += 256) s += partials[i];
    red[threadIdx.x] = s;
    __syncthreads();
    #pragma unroll
    for (int step = 128; step > 0; step >>= 1) {
        if ((int)threadIdx.x < step) red[threadIdx.x] += red[threadIdx.x + step];
        __syncthreads();
    }
    if (threadIdx.x == 0) {
        double m = red[0] * invND;
        out_loss[0] = (float)(0.25 * m + m);
    }
}

extern "C" void kernel_launch(void* const* d_in, const int* in_sizes, int n_in,
                              void* d_out, int out_size, void* d_ws, size_t ws_size,
                              hipStream_t stream)
{
    const float* x  = (const float*)d_in[0];
    const float* cb = (const float*)d_in[1];
    const int N = in_sizes[0] / D;   // 65536
    const int K = in_sizes[1] / D;   // 4096

    float* out      = (float*)d_out;
    float* out_q    = out;
    float* out_i    = out + (size_t)N * D;
    float* out_loss = out_i + N;

    char* ws = (char*)d_ws;
    bf16x8* cbf      = (bf16x8*)ws;                       // 512 KB
    size_t off = (size_t)(K / 16) * 2 * 64 * sizeof(bf16x8);
    double* partials = (double*)(ws + off); off += (size_t)(N / 4) * sizeof(double);
    float*  sx       = (float*)(ws + off);  off += (size_t)N * sizeof(float);
    float*  sc       = (float*)(ws + off);  off += (size_t)K * sizeof(float);
    int*    idxbuf   = (int*)(ws + off);    off += (size_t)N * sizeof(int);
    int*    ovf_rows = (int*)(ws + off);    off += (size_t)N * sizeof(int);
    int*    ovf_cnt  = (int*)(ws + off);

    hipMemsetAsync(ovf_cnt, 0, sizeof(int), stream);
    rowsumsq_kernel<<<(N + 255) / 256, 256, 0, stream>>>(x, sx, N);
    rowsumsq_kernel<<<(K + 255) / 256, 256, 0, stream>>>(cb, sc, K);
    pack_cb<<<K / 16, 128, 0, stream>>>(cb, cbf);
    phase1_kernel<<<N / 64, 256, 0, stream>>>(x, cb, sx, sc, cbf, idxbuf, ovf_cnt, ovf_rows);
    fallback_kernel<<<16, 256, 0, stream>>>(x, cb, sx, sc, ovf_cnt, ovf_rows, idxbuf);
    finalize_rows<<<N / 4, 256, 0, stream>>>(x, cb, idxbuf, out_q, out_i, partials, N);
    loss_kernel<<<1, 256, 0, stream>>>(partials, N / 4, out_loss,
                                       1.0 / ((double)N * (double)D));
}

// Round 5
// 348.294 us; speedup vs baseline: 73.9763x; 73.9763x over previous
//
#include <hip/hip_runtime.h>

// VQ quantizer: N=65536 rows (D=64) vs K=4096 codes. d_out = FLOAT32
// [x_quantized N*D][indices N][loss 1].
//
// Round-5: split-bf16 MFMA scoring (xh+xl, ch+cl; 3 cross terms = 6 MFMA) gives
// |approx - exact_f32chain| <= ~3e-6 + s*1.2e-7. Per-row top-2 (m1,i1,m2):
// if m2-m1 > marg the approx winner IS the reference argmin (strict, tie-safe).
// Ambiguous rows (~4-8k expected) -> LDS-tiled exact sequential-FMA rescan.

#define D  64
#define NT 256   // K/16 code tiles

typedef unsigned short u16;
typedef short bf16x8 __attribute__((ext_vector_type(8)));
typedef float f32x4  __attribute__((ext_vector_type(4)));

__device__ __forceinline__ u16 f32_to_bf16_raw(float f) {
    union { float f; unsigned u; } v; v.f = f;
    unsigned u = v.u;
    u += 0x7FFFu + ((u >> 16) & 1u);   // RNE
    return (u16)(u >> 16);
}
__device__ __forceinline__ float bf16_raw_to_f32(u16 h) {
    union { unsigned u; float f; } v; v.u = ((unsigned)h) << 16;
    return v.f;
}
__device__ __forceinline__ f32x4 mfma16(bf16x8 a, bf16x8 b, f32x4 c) {
    return __builtin_amdgcn_mfma_f32_16x16x32_bf16(a, b, c, 0, 0, 0);
}

// ---------- numpy-exact row sum of squares (pairwise n=64), proven in R3 ----------
__device__ __forceinline__ float np_pairwise_sumsq_64(const float* p) {
    float r[8];
    #pragma unroll
    for (int j = 0; j < 8; ++j) r[j] = __fmul_rn(p[j], p[j]);
    #pragma unroll
    for (int i = 8; i < 64; i += 8) {
        #pragma unroll
        for (int j = 0; j < 8; ++j)
            r[j] = __fadd_rn(r[j], __fmul_rn(p[i + j], p[i + j]));
    }
    float t0 = __fadd_rn(r[0], r[1]);
    float t1 = __fadd_rn(r[2], r[3]);
    float t2 = __fadd_rn(r[4], r[5]);
    float t3 = __fadd_rn(r[6], r[7]);
    return __fadd_rn(__fadd_rn(t0, t1), __fadd_rn(t2, t3));
}

__global__ __launch_bounds__(256) void rowsumsq_kernel(const float* __restrict__ a,
                                                       float* __restrict__ out, int nrows) {
    int r = blockIdx.x * 256 + threadIdx.x;
    if (r >= nrows) return;
    float buf[64];
    const float4* p = (const float4*)(a + (size_t)r * D);
    #pragma unroll
    for (int i = 0; i < 16; ++i) {
        float4 v = p[i];
        buf[4*i] = v.x; buf[4*i+1] = v.y; buf[4*i+2] = v.z; buf[4*i+3] = v.w;
    }
    out[r] = np_pairwise_sumsq_64(buf);
}

// ---------- pack codebook: head (hl=0) and tail (hl=1) bf16 B-fragments, 1MB ----------
// frag (t, hl, ks, lane): code = t*16+(lane&15); d = ks*32 + g*4 + (j&3) + 16*(j>>2),
// g = lane>>4. Same (g,j)->k rule as the A-side pack, so k-map errors cancel.
__global__ __launch_bounds__(256) void pack_cb2(const float* __restrict__ cb,
                                                bf16x8* __restrict__ cbf) {
    int t = blockIdx.x;
    int tid = threadIdx.x;
    int lane = tid & 63;
    int ks = (tid >> 6) & 1;
    int hl = tid >> 7;
    int code = t * 16 + (lane & 15);
    int g = lane >> 4;
    bf16x8 v;
    #pragma unroll
    for (int j = 0; j < 8; ++j) {
        int d = ks * 32 + g * 4 + (j & 3) + 16 * (j >> 2);
        float val = cb[(size_t)code * D + d];
        u16 h = f32_to_bf16_raw(val);
        if (hl) {
            float resid = val - bf16_raw_to_f32(h);   // exact (Sterbenz)
            h = f32_to_bf16_raw(resid);
        }
        v[j] = (short)h;
    }
    cbf[((size_t)t * 4 + hl * 2 + ks) * 64 + lane] = v;
}

// ---------- phase 1: split-bf16 MFMA top-2 scan ----------
// 512 threads = 8 waves; wave owns 32 rows (two 16x16 subtiles sharing B reads).
// B tiles (4KB: [hl][ks][lane]x16B) double-buffered in LDS via global_load_lds.
#define MARG_A 8.0e-6f
#define MARG_B 5.0e-7f

__global__ __launch_bounds__(512) void phase1_kernel(
    const float* __restrict__ x, const float* __restrict__ sx,
    const float* __restrict__ sc, const bf16x8* __restrict__ cbf,
    int* __restrict__ idxbuf, int* __restrict__ amb_cnt, int* __restrict__ amb_rows)
{
    __shared__ __align__(16) char lds[2][4096];

    const int tid  = threadIdx.x;
    const int w    = tid >> 6;
    const int lane = tid & 63;
    const int r = lane & 15, g = lane >> 4;
    const int rowA = blockIdx.x * 256 + w * 32 + r;      // A-side row this lane loads
    const int rowB = rowA + 16;

    // build A fragments (head+tail) for rows rowA, rowB
    bf16x8 A0h, A1h, A0l, A1l, B0h, B1h, B0l, B1l;
    {
        const float* xr = x + (size_t)rowA * D;
        float e0[8], e1[8];
        float4 f0 = *(const float4*)(xr + g * 4);
        float4 f1 = *(const float4*)(xr + 16 + g * 4);
        float4 f2 = *(const float4*)(xr + 32 + g * 4);
        float4 f3 = *(const float4*)(xr + 48 + g * 4);
        e0[0]=f0.x;e0[1]=f0.y;e0[2]=f0.z;e0[3]=f0.w; e0[4]=f1.x;e0[5]=f1.y;e0[6]=f1.z;e0[7]=f1.w;
        e1[0]=f2.x;e1[1]=f2.y;e1[2]=f2.z;e1[3]=f2.w; e1[4]=f3.x;e1[5]=f3.y;e1[6]=f3.z;e1[7]=f3.w;
        #pragma unroll
        for (int j = 0; j < 8; ++j) {
            u16 h0 = f32_to_bf16_raw(e0[j]);
            A0h[j] = (short)h0; A0l[j] = (short)f32_to_bf16_raw(e0[j] - bf16_raw_to_f32(h0));
            u16 h1 = f32_to_bf16_raw(e1[j]);
            A1h[j] = (short)h1; A1l[j] = (short)f32_to_bf16_raw(e1[j] - bf16_raw_to_f32(h1));
        }
    }
    {
        const float* xr = x + (size_t)rowB * D;
        float e0[8], e1[8];
        float4 f0 = *(const float4*)(xr + g * 4);
        float4 f1 = *(const float4*)(xr + 16 + g * 4);
        float4 f2 = *(const float4*)(xr + 32 + g * 4);
        float4 f3 = *(const float4*)(xr + 48 + g * 4);
        e0[0]=f0.x;e0[1]=f0.y;e0[2]=f0.z;e0[3]=f0.w; e0[4]=f1.x;e0[5]=f1.y;e0[6]=f1.z;e0[7]=f1.w;
        e1[0]=f2.x;e1[1]=f2.y;e1[2]=f2.z;e1[3]=f2.w; e1[4]=f3.x;e1[5]=f3.y;e1[6]=f3.z;e1[7]=f3.w;
        #pragma unroll
        for (int j = 0; j < 8; ++j) {
            u16 h0 = f32_to_bf16_raw(e0[j]);
            B0h[j] = (short)h0; B0l[j] = (short)f32_to_bf16_raw(e0[j] - bf16_raw_to_f32(h0));
            u16 h1 = f32_to_bf16_raw(e1[j]);
            B1h[j] = (short)h1; B1l[j] = (short)f32_to_bf16_raw(e1[j] - bf16_raw_to_f32(h1));
        }
    }

    // output rows for state u in [0,8): orow(u) = blk*256 + w*32 + (u>>2)*16 + g*4 + (u&3)
    float sxr[8], m1[8], m2[8];
    int   i1[8];
    #pragma unroll
    for (int u = 0; u < 8; ++u) {
        int orow = blockIdx.x * 256 + w * 32 + (u >> 2) * 16 + g * 4 + (u & 3);
        sxr[u] = sx[orow];
        m1[u] = 3.4e38f; m2[u] = 3.4e38f; i1[u] = 0;
    }

    // staging lambda: waves 0-3 each stage 1KB of tile t into lds[buf]
    auto stage = [&](int t, int buf) {
        if (w < 4) {
            const char* src = (const char*)cbf + (size_t)t * 4096 + w * 1024 + lane * 16;
            __builtin_amdgcn_global_load_lds(
                (const __attribute__((address_space(1))) unsigned int*)src,
                (__attribute__((address_space(3))) unsigned int*)&lds[buf][w * 1024 + lane * 16],
                16, 0, 0);
        }
    };

    stage(0, 0);
    asm volatile("s_waitcnt vmcnt(0)" ::: "memory");
    __syncthreads();

    for (int t = 0; t < NT; ++t) {
        int cur = t & 1;
        if (t + 1 < NT) stage(t + 1, cur ^ 1);

        const bf16x8* bf = (const bf16x8*)lds[cur];
        bf16x8 b0h = bf[0 * 64 + lane];
        bf16x8 b1h = bf[1 * 64 + lane];
        bf16x8 b0l = bf[2 * 64 + lane];
        bf16x8 b1l = bf[3 * 64 + lane];

        f32x4 accA = {0.f, 0.f, 0.f, 0.f};
        f32x4 accB = {0.f, 0.f, 0.f, 0.f};
        accA = mfma16(A0h, b0h, accA);  accB = mfma16(B0h, b0h, accB);
        accA = mfma16(A1h, b1h, accA);  accB = mfma16(B1h, b1h, accB);
        accA = mfma16(A0h, b0l, accA);  accB = mfma16(B0h, b0l, accB);
        accA = mfma16(A1h, b1l, accA);  accB = mfma16(B1h, b1l, accB);
        accA = mfma16(A0l, b0h, accA);  accB = mfma16(B0l, b0h, accB);
        accA = mfma16(A1l, b1h, accA);  accB = mfma16(B1l, b1h, accB);

        float sck = sc[t * 16 + r];
        int   kc  = t * 16 + r;
        #pragma unroll
        for (int q = 0; q < 4; ++q) {
            float s = __fmaf_rn(-2.0f, accA[q], __fadd_rn(sxr[q], sck));
            m2[q] = fminf(m2[q], fmaxf(m1[q], s));
            bool lt = s < m1[q];
            i1[q] = lt ? kc : i1[q];
            m1[q] = fminf(m1[q], s);
        }
        #pragma unroll
        for (int q = 0; q < 4; ++q) {
            float s = __fmaf_rn(-2.0f, accB[q], __fadd_rn(sxr[4 + q], sck));
            m2[4+q] = fminf(m2[4+q], fmaxf(m1[4+q], s));
            bool lt = s < m1[4+q];
            i1[4+q] = lt ? kc : i1[4+q];
            m1[4+q] = fminf(m1[4+q], s);
        }

        asm volatile("s_waitcnt vmcnt(0)" ::: "memory");
        __syncthreads();
    }

    // merge top-2 across the 16 code-lanes (same g group)
    #pragma unroll
    for (int u = 0; u < 8; ++u) {
        #pragma unroll
        for (int mm = 1; mm < 16; mm <<= 1) {
            float om1 = __shfl_xor(m1[u], mm, 64);
            float om2 = __shfl_xor(m2[u], mm, 64);
            int   oi1 = __shfl_xor(i1[u], mm, 64);
            float nm2 = fminf(fmaxf(m1[u], om1), fminf(m2[u], om2));
            i1[u] = (om1 < m1[u]) ? oi1 : i1[u];
            m1[u] = fminf(m1[u], om1);
            m2[u] = nm2;
        }
    }
    if (r == 0) {
        #pragma unroll
        for (int u = 0; u < 8; ++u) {
            int orow = blockIdx.x * 256 + w * 32 + (u >> 2) * 16 + g * 4 + (u & 3);
            idxbuf[orow] = i1[u];
            float marg = __fmaf_rn(sxr[u], MARG_B, MARG_A);
            if (m2[u] - m1[u] <= marg) {
                int slot = atomicAdd(amb_cnt, 1);
                amb_rows[slot] = orow;
            }
        }
    }
}

// ---------- exact rescan of ambiguous rows (reference-exact f32 FMA chains) ----------
// chunk = 16 rows; per super-iter stage 256 codes (4 LDS tiles) transposed; thread
// (tz,ty,cx) = 4 rows x 4 codes; lex (score,idx) argmin, first-min semantics.
__global__ __launch_bounds__(256) void exact_scan(
    const float* __restrict__ x, const float* __restrict__ cb,
    const float* __restrict__ sx, const float* __restrict__ sc,
    const int* __restrict__ amb_cnt, const int* __restrict__ amb_rows,
    int* __restrict__ idxbuf)
{
    __shared__ float csT[4][64][64];   // [tz][d][code]
    __shared__ float xsT[64][16];      // [d][row]
    __shared__ float redv[16][64];
    __shared__ int   redi[16][64];
    __shared__ float sxl[16];
    __shared__ int   rowids[16];

    const int tid = threadIdx.x;
    const int cnt = *amb_cnt;
    const int tz = tid >> 6, ty = (tid >> 4) & 3, cx = tid & 15;

    for (int base = blockIdx.x * 16; base < cnt; base += gridDim.x * 16) {
        if (tid < 16) {
            int i = base + tid;
            int rr = (i < cnt) ? amb_rows[i] : amb_rows[base];  // pad with row0 (harmless rewrite)
            rowids[tid] = rr;
            sxl[tid] = sx[rr];
        }
        __syncthreads();
        {   // stage x rows transposed
            int rr = rowids[tid >> 4];
            int dg = tid & 15;
            float4 v = *(const float4*)(x + (size_t)rr * D + dg * 4);
            xsT[dg*4+0][tid>>4] = v.x; xsT[dg*4+1][tid>>4] = v.y;
            xsT[dg*4+2][tid>>4] = v.z; xsT[dg*4+3][tid>>4] = v.w;
        }

        float bv[4]; int bi[4];
        #pragma unroll
        for (int i = 0; i < 4; ++i) { bv[i] = 3.4e38f; bi[i] = 0x7fffffff; }

        for (int st = 0; st < 16; ++st) {
            __syncthreads();   // protect csT before overwrite
            {   // stage 256 codes (this thread: one code, all 64 dims)
                int code = st * 256 + tid;
                const float4* src = (const float4*)(cb + (size_t)code * D);
                #pragma unroll
                for (int dd = 0; dd < 16; ++dd) {
                    float4 v = src[dd];
                    csT[tid>>6][dd*4+0][tid&63] = v.x; csT[tid>>6][dd*4+1][tid&63] = v.y;
                    csT[tid>>6][dd*4+2][tid&63] = v.z; csT[tid>>6][dd*4+3][tid&63] = v.w;
                }
            }
            __syncthreads();

            float acc[4][4];
            #pragma unroll
            for (int i = 0; i < 4; ++i)
                #pragma unroll
                for (int j = 0; j < 4; ++j) acc[i][j] = 0.0f;

            #pragma unroll 4
            for (int d = 0; d < 64; ++d) {          // d ascending: ref-exact FMA chains
                float4 xv = *(const float4*)&xsT[d][ty * 4];
                float4 cv = *(const float4*)&csT[tz][d][cx * 4];
                float xr[4] = {xv.x, xv.y, xv.z, xv.w};
                float cc[4] = {cv.x, cv.y, cv.z, cv.w};
                #pragma unroll
                for (int i = 0; i < 4; ++i)
                    #pragma unroll
                    for (int j = 0; j < 4; ++j)
                        acc[i][j] = __fmaf_rn(xr[i], cc[j], acc[i][j]);
            }
            #pragma unroll
            for (int j = 0; j < 4; ++j) {
                int k = st * 256 + tz * 64 + cx * 4 + j;
                float sck = sc[k];
                #pragma unroll
                for (int i = 0; i < 4; ++i) {
                    float tt = __fadd_rn(sxl[ty * 4 + i], sck);
                    float u  = __fmul_rn(2.0f, acc[i][j]);
                    float s  = __fsub_rn(tt, u);
                    if (s < bv[i] || (s == bv[i] && k < bi[i])) { bv[i] = s; bi[i] = k; }
                }
            }
        }

        #pragma unroll
        for (int i = 0; i < 4; ++i) { redv[ty*4+i][tz*16+cx] = bv[i]; redi[ty*4+i][tz*16+cx] = bi[i]; }
        __syncthreads();
        if (tid < 16) {
            float bvv = redv[tid][0]; int bii = redi[tid][0];
            #pragma unroll 8
            for (int i = 1; i < 64; ++i) {
                float v = redv[tid][i]; int k = redi[tid][i];
                if (v < bvv || (v == bvv && k < bii)) { bvv = v; bii = k; }
            }
            idxbuf[rowids[tid]] = bii;
        }
        __syncthreads();
    }
}

// ---------- finalize + loss (unchanged, PASS-verified) ----------
__global__ __launch_bounds__(256) void finalize_rows(
    const float* __restrict__ x, const float* __restrict__ cb,
    const int* __restrict__ idxbuf,
    float* __restrict__ out_q, float* __restrict__ out_i,
    double* __restrict__ partials, int N)
{
    __shared__ double wsum[4];
    int wid = threadIdx.x >> 6, lane = threadIdx.x & 63;
    int n = blockIdx.x * 4 + wid;

    int idx = idxbuf[n];
    float q  = cb[(size_t)idx * D + lane];
    float xv = x[(size_t)n * D + lane];
    out_q[(size_t)n * D + lane] = q;

    double diff = (double)xv - (double)q;
    double s = diff * diff;
    #pragma unroll
    for (int off = 32; off > 0; off >>= 1) s += __shfl_down(s, off, 64);
    if (lane == 0) { wsum[wid] = s; out_i[n] = (float)idx; }
    __syncthreads();
    if (threadIdx.x == 0) partials[blockIdx.x] = (wsum[0] + wsum[1]) + (wsum[2] + wsum[3]);
}

__global__ __launch_bounds__(256) void loss_kernel(const double* __restrict__ partials,
                                                   int nP, float* __restrict__ out_loss,
                                                   double invND)
{
    __shared__ double red[256];
    double s = 0.0;
    for (int i = threadIdx.x; i < nP; i += 256) s += partials[i];
    red[threadIdx.x] = s;
    __syncthreads();
    #pragma unroll
    for (int step = 128; step > 0; step >>= 1) {
        if ((int)threadIdx.x < step) red[threadIdx.x] += red[threadIdx.x + step];
        __syncthreads();
    }
    if (threadIdx.x == 0) {
        double m = red[0] * invND;
        out_loss[0] = (float)(0.25 * m + m);
    }
}

extern "C" void kernel_launch(void* const* d_in, const int* in_sizes, int n_in,
                              void* d_out, int out_size, void* d_ws, size_t ws_size,
                              hipStream_t stream)
{
    const float* x  = (const float*)d_in[0];
    const float* cb = (const float*)d_in[1];
    const int N = in_sizes[0] / D;   // 65536
    const int K = in_sizes[1] / D;   // 4096

    float* out      = (float*)d_out;
    float* out_q    = out;
    float* out_i    = out + (size_t)N * D;
    float* out_loss = out_i + N;

    char* ws = (char*)d_ws;
    bf16x8* cbf      = (bf16x8*)ws;                         // 1 MB
    size_t off = (size_t)(K / 16) * 4 * 64 * sizeof(bf16x8);
    float*  sx       = (float*)(ws + off);  off += (size_t)N * 4;
    float*  sc       = (float*)(ws + off);  off += (size_t)K * 4;
    int*    idxbuf   = (int*)(ws + off);    off += (size_t)N * 4;
    int*    amb_rows = (int*)(ws + off);    off += (size_t)N * 4;
    double* partials = (double*)(ws + off); off += (size_t)(N / 4) * 8;
    int*    amb_cnt  = (int*)(ws + off);

    hipMemsetAsync(amb_cnt, 0, sizeof(int), stream);
    rowsumsq_kernel<<<(N + 255) / 256, 256, 0, stream>>>(x, sx, N);
    rowsumsq_kernel<<<(K + 255) / 256, 256, 0, stream>>>(cb, sc, K);
    pack_cb2<<<K / 16, 256, 0, stream>>>(cb, cbf);
    phase1_kernel<<<N / 256, 512, 0, stream>>>(x, sx, sc, cbf, idxbuf, amb_cnt, amb_rows);
    exact_scan<<<512, 256, 0, stream>>>(x, cb, sx, sc, amb_cnt, amb_rows, idxbuf);
    finalize_rows<<<N / 4, 256, 0, stream>>>(x, cb, idxbuf, out_q, out_i, partials, N);
    loss_kernel<<<1, 256, 0, stream>>>(partials, N / 4, out_loss,
                                       1.0 / ((double)N * (double)D));
}

// Round 6
// 303.141 us; speedup vs baseline: 84.9953x; 1.1490x over previous
//
#include <hip/hip_runtime.h>

// VQ quantizer: N=65536 rows (D=64) vs K=4096 codes. d_out = FLOAT32
// [x_quantized N*D][indices N][loss 1].
//
// Round-6: phase1 rescheduled (math identical to PASS round-5):
//  - 256-thr blocks (4 waves, 128 rows), grid 512 -> 2 blocks/CU
//  - 8KB phases (2 code-tiles), 4-deep LDS ring, prefetch-3, counted vmcnt
//    (never vmcnt(0) in loop), barrier per phase without drain
//  - sc[] staged in LDS: the K-loop has no global vector-mem ops except the
//    counted global_load_lds -> vmcnt arithmetic is exact.

#define D  64
#define NT 256          // K/16 code tiles
#define PH 128          // phases (2 tiles each)

typedef unsigned short u16;
typedef short bf16x8 __attribute__((ext_vector_type(8)));
typedef float f32x4  __attribute__((ext_vector_type(4)));

#define VMWAIT(n) asm volatile("s_waitcnt vmcnt(" #n ")" ::: "memory")

__device__ __forceinline__ u16 f32_to_bf16_raw(float f) {
    union { float f; unsigned u; } v; v.f = f;
    unsigned u = v.u;
    u += 0x7FFFu + ((u >> 16) & 1u);   // RNE
    return (u16)(u >> 16);
}
__device__ __forceinline__ float bf16_raw_to_f32(u16 h) {
    union { unsigned u; float f; } v; v.u = ((unsigned)h) << 16;
    return v.f;
}
__device__ __forceinline__ f32x4 mfma16(bf16x8 a, bf16x8 b, f32x4 c) {
    return __builtin_amdgcn_mfma_f32_16x16x32_bf16(a, b, c, 0, 0, 0);
}

// ---------- numpy-exact row sum of squares (pairwise n=64), proven R3 ----------
__device__ __forceinline__ float np_pairwise_sumsq_64(const float* p) {
    float r[8];
    #pragma unroll
    for (int j = 0; j < 8; ++j) r[j] = __fmul_rn(p[j], p[j]);
    #pragma unroll
    for (int i = 8; i < 64; i += 8) {
        #pragma unroll
        for (int j = 0; j < 8; ++j)
            r[j] = __fadd_rn(r[j], __fmul_rn(p[i + j], p[i + j]));
    }
    float t0 = __fadd_rn(r[0], r[1]);
    float t1 = __fadd_rn(r[2], r[3]);
    float t2 = __fadd_rn(r[4], r[5]);
    float t3 = __fadd_rn(r[6], r[7]);
    return __fadd_rn(__fadd_rn(t0, t1), __fadd_rn(t2, t3));
}

__global__ __launch_bounds__(256) void rowsumsq_kernel(const float* __restrict__ a,
                                                       float* __restrict__ out, int nrows) {
    int r = blockIdx.x * 256 + threadIdx.x;
    if (r >= nrows) return;
    float buf[64];
    const float4* p = (const float4*)(a + (size_t)r * D);
    #pragma unroll
    for (int i = 0; i < 16; ++i) {
        float4 v = p[i];
        buf[4*i] = v.x; buf[4*i+1] = v.y; buf[4*i+2] = v.z; buf[4*i+3] = v.w;
    }
    out[r] = np_pairwise_sumsq_64(buf);
}

// ---------- pack codebook: head/tail bf16 B-fragments (1MB), proven R5 ----------
__global__ __launch_bounds__(256) void pack_cb2(const float* __restrict__ cb,
                                                bf16x8* __restrict__ cbf) {
    int t = blockIdx.x;
    int tid = threadIdx.x;
    int lane = tid & 63;
    int ks = (tid >> 6) & 1;
    int hl = tid >> 7;
    int code = t * 16 + (lane & 15);
    int g = lane >> 4;
    bf16x8 v;
    #pragma unroll
    for (int j = 0; j < 8; ++j) {
        int d = ks * 32 + g * 4 + (j & 3) + 16 * (j >> 2);
        float val = cb[(size_t)code * D + d];
        u16 h = f32_to_bf16_raw(val);
        if (hl) {
            float resid = val - bf16_raw_to_f32(h);   // exact (Sterbenz)
            h = f32_to_bf16_raw(resid);
        }
        v[j] = (short)h;
    }
    cbf[((size_t)t * 4 + hl * 2 + ks) * 64 + lane] = v;
}

// ---------- phase 1: split-bf16 MFMA top-2 scan, pipelined ----------
#define MARG_A 8.0e-6f
#define MARG_B 5.0e-7f

__global__ __launch_bounds__(256, 2) void phase1_kernel(
    const float* __restrict__ x, const float* __restrict__ sx,
    const float* __restrict__ sc, const bf16x8* __restrict__ cbf,
    int* __restrict__ idxbuf, int* __restrict__ amb_cnt, int* __restrict__ amb_rows)
{
    __shared__ __align__(16) char ring[4][8192];   // 4-deep ring of 8KB phases
    __shared__ float scl[4096];                     // sc staged in LDS

    const int tid  = threadIdx.x;
    const int w    = tid >> 6;
    const int lane = tid & 63;
    const int r = lane & 15, g = lane >> 4;
    const int rowA = blockIdx.x * 128 + w * 32 + r;
    const int rowB = rowA + 16;

    // stage sc into LDS (vectorized; before the vmcnt reset)
    for (int j = tid; j < 1024; j += 256)
        *(float4*)&scl[j * 4] = *(const float4*)&sc[j * 4];

    // build A fragments (head+tail) for rows rowA, rowB — identical to R5
    bf16x8 A0h, A1h, A0l, A1l, B0h, B1h, B0l, B1l;
    {
        const float* xr = x + (size_t)rowA * D;
        float e0[8], e1[8];
        float4 f0 = *(const float4*)(xr + g * 4);
        float4 f1 = *(const float4*)(xr + 16 + g * 4);
        float4 f2 = *(const float4*)(xr + 32 + g * 4);
        float4 f3 = *(const float4*)(xr + 48 + g * 4);
        e0[0]=f0.x;e0[1]=f0.y;e0[2]=f0.z;e0[3]=f0.w; e0[4]=f1.x;e0[5]=f1.y;e0[6]=f1.z;e0[7]=f1.w;
        e1[0]=f2.x;e1[1]=f2.y;e1[2]=f2.z;e1[3]=f2.w; e1[4]=f3.x;e1[5]=f3.y;e1[6]=f3.z;e1[7]=f3.w;
        #pragma unroll
        for (int j = 0; j < 8; ++j) {
            u16 h0 = f32_to_bf16_raw(e0[j]);
            A0h[j] = (short)h0; A0l[j] = (short)f32_to_bf16_raw(e0[j] - bf16_raw_to_f32(h0));
            u16 h1 = f32_to_bf16_raw(e1[j]);
            A1h[j] = (short)h1; A1l[j] = (short)f32_to_bf16_raw(e1[j] - bf16_raw_to_f32(h1));
        }
    }
    {
        const float* xr = x + (size_t)rowB * D;
        float e0[8], e1[8];
        float4 f0 = *(const float4*)(xr + g * 4);
        float4 f1 = *(const float4*)(xr + 16 + g * 4);
        float4 f2 = *(const float4*)(xr + 32 + g * 4);
        float4 f3 = *(const float4*)(xr + 48 + g * 4);
        e0[0]=f0.x;e0[1]=f0.y;e0[2]=f0.z;e0[3]=f0.w; e0[4]=f1.x;e0[5]=f1.y;e0[6]=f1.z;e0[7]=f1.w;
        e1[0]=f2.x;e1[1]=f2.y;e1[2]=f2.z;e1[3]=f2.w; e1[4]=f3.x;e1[5]=f3.y;e1[6]=f3.z;e1[7]=f3.w;
        #pragma unroll
        for (int j = 0; j < 8; ++j) {
            u16 h0 = f32_to_bf16_raw(e0[j]);
            B0h[j] = (short)h0; B0l[j] = (short)f32_to_bf16_raw(e0[j] - bf16_raw_to_f32(h0));
            u16 h1 = f32_to_bf16_raw(e1[j]);
            B1h[j] = (short)h1; B1l[j] = (short)f32_to_bf16_raw(e1[j] - bf16_raw_to_f32(h1));
        }
    }

    float sxr[8], m1[8], m2[8];
    int   i1[8];
    #pragma unroll
    for (int u = 0; u < 8; ++u) {
        int orow = blockIdx.x * 128 + w * 32 + (u >> 2) * 16 + g * 4 + (u & 3);
        sxr[u] = sx[orow];
        m1[u] = 3.4e38f; m2[u] = 3.4e38f; i1[u] = 0;
    }

    // stage phase p (8KB = tiles 2p,2p+1): each thread issues exactly 2 loads.
    auto stage = [&](int p, int buf) {
        const char* src = (const char*)cbf + (size_t)p * 8192 + tid * 16;
        #pragma unroll
        for (int i = 0; i < 2; ++i) {
            __builtin_amdgcn_global_load_lds(
                (const __attribute__((address_space(1))) unsigned int*)(src + i * 4096),
                (__attribute__((address_space(3))) unsigned int*)&ring[buf][i * 4096 + w * 1024 + lane * 16],
                16, 0, 0);
        }
    };

    // compute one phase (2 code-tiles) from ring[buf]
    auto compute = [&](int p, int buf) {
        #pragma unroll
        for (int tt = 0; tt < 2; ++tt) {
            int t = 2 * p + tt;
            const bf16x8* bf = (const bf16x8*)&ring[buf][tt * 4096];
            bf16x8 b0h = bf[0 * 64 + lane];
            bf16x8 b1h = bf[1 * 64 + lane];
            bf16x8 b0l = bf[2 * 64 + lane];
            bf16x8 b1l = bf[3 * 64 + lane];

            f32x4 accA = {0.f, 0.f, 0.f, 0.f};
            f32x4 accB = {0.f, 0.f, 0.f, 0.f};
            accA = mfma16(A0h, b0h, accA);  accB = mfma16(B0h, b0h, accB);
            accA = mfma16(A1h, b1h, accA);  accB = mfma16(B1h, b1h, accB);
            accA = mfma16(A0h, b0l, accA);  accB = mfma16(B0h, b0l, accB);
            accA = mfma16(A1h, b1l, accA);  accB = mfma16(B1h, b1l, accB);
            accA = mfma16(A0l, b0h, accA);  accB = mfma16(B0l, b0h, accB);
            accA = mfma16(A1l, b1h, accA);  accB = mfma16(B1l, b1h, accB);

            float sck = scl[t * 16 + r];
            int   kc  = t * 16 + r;
            #pragma unroll
            for (int q = 0; q < 4; ++q) {
                float s = __fmaf_rn(-2.0f, accA[q], __fadd_rn(sxr[q], sck));
                m2[q] = fminf(m2[q], fmaxf(m1[q], s));
                bool lt = s < m1[q];
                i1[q] = lt ? kc : i1[q];
                m1[q] = fminf(m1[q], s);
            }
            #pragma unroll
            for (int q = 0; q < 4; ++q) {
                float s = __fmaf_rn(-2.0f, accB[q], __fadd_rn(sxr[4 + q], sck));
                m2[4+q] = fminf(m2[4+q], fmaxf(m1[4+q], s));
                bool lt = s < m1[4+q];
                i1[4+q] = lt ? kc : i1[4+q];
                m1[4+q] = fminf(m1[4+q], s);
            }
        }
    };

    // pipeline: prefetch 3 phases, counted vmcnt (2 loads per stage call)
    VMWAIT(0);                         // normalize counter (x/sx/sc loads drained)
    stage(0, 0); stage(1, 1); stage(2, 2);   // outstanding = 6

    for (int p = 0; p < PH - 3; ++p) {
        VMWAIT(4);                     // retire phase p's 2 loads (oldest)
        __syncthreads();               // p's tile visible to all waves
        stage(p + 3, (p + 3) & 3);     // overlaps compute; targets buf read at p-1
        compute(p, p & 3);
    }
    VMWAIT(4); __syncthreads(); compute(PH - 3, (PH - 3) & 3);
    VMWAIT(2); __syncthreads(); compute(PH - 2, (PH - 2) & 3);
    VMWAIT(0); __syncthreads(); compute(PH - 1, (PH - 1) & 3);

    // merge top-2 across the 16 code-lanes (same g group) — identical to R5
    #pragma unroll
    for (int u = 0; u < 8; ++u) {
        #pragma unroll
        for (int mm = 1; mm < 16; mm <<= 1) {
            float om1 = __shfl_xor(m1[u], mm, 64);
            float om2 = __shfl_xor(m2[u], mm, 64);
            int   oi1 = __shfl_xor(i1[u], mm, 64);
            float nm2 = fminf(fmaxf(m1[u], om1), fminf(m2[u], om2));
            i1[u] = (om1 < m1[u]) ? oi1 : i1[u];
            m1[u] = fminf(m1[u], om1);
            m2[u] = nm2;
        }
    }
    if (r == 0) {
        #pragma unroll
        for (int u = 0; u < 8; ++u) {
            int orow = blockIdx.x * 128 + w * 32 + (u >> 2) * 16 + g * 4 + (u & 3);
            idxbuf[orow] = i1[u];
            float marg = __fmaf_rn(sxr[u], MARG_B, MARG_A);
            if (m2[u] - m1[u] <= marg) {
                int slot = atomicAdd(amb_cnt, 1);
                amb_rows[slot] = orow;
            }
        }
    }
}

// ---------- exact rescan of ambiguous rows (reference-exact f32), proven R5 ----------
__global__ __launch_bounds__(256) void exact_scan(
    const float* __restrict__ x, const float* __restrict__ cb,
    const float* __restrict__ sx, const float* __restrict__ sc,
    const int* __restrict__ amb_cnt, const int* __restrict__ amb_rows,
    int* __restrict__ idxbuf)
{
    __shared__ float csT[4][64][64];   // [tz][d][code]
    __shared__ float xsT[64][16];      // [d][row]
    __shared__ float redv[16][64];
    __shared__ int   redi[16][64];
    __shared__ float sxl[16];
    __shared__ int   rowids[16];

    const int tid = threadIdx.x;
    const int cnt = *amb_cnt;
    const int tz = tid >> 6, ty = (tid >> 4) & 3, cx = tid & 15;

    for (int base = blockIdx.x * 16; base < cnt; base += gridDim.x * 16) {
        if (tid < 16) {
            int i = base + tid;
            int rr = (i < cnt) ? amb_rows[i] : amb_rows[base];
            rowids[tid] = rr;
            sxl[tid] = sx[rr];
        }
        __syncthreads();
        {
            int rr = rowids[tid >> 4];
            int dg = tid & 15;
            float4 v = *(const float4*)(x + (size_t)rr * D + dg * 4);
            xsT[dg*4+0][tid>>4] = v.x; xsT[dg*4+1][tid>>4] = v.y;
            xsT[dg*4+2][tid>>4] = v.z; xsT[dg*4+3][tid>>4] = v.w;
        }

        float bv[4]; int bi[4];
        #pragma unroll
        for (int i = 0; i < 4; ++i) { bv[i] = 3.4e38f; bi[i] = 0x7fffffff; }

        for (int st = 0; st < 16; ++st) {
            __syncthreads();
            {
                int code = st * 256 + tid;
                const float4* src = (const float4*)(cb + (size_t)code * D);
                #pragma unroll
                for (int dd = 0; dd < 16; ++dd) {
                    float4 v = src[dd];
                    csT[tid>>6][dd*4+0][tid&63] = v.x; csT[tid>>6][dd*4+1][tid&63] = v.y;
                    csT[tid>>6][dd*4+2][tid&63] = v.z; csT[tid>>6][dd*4+3][tid&63] = v.w;
                }
            }
            __syncthreads();

            float acc[4][4];
            #pragma unroll
            for (int i = 0; i < 4; ++i)
                #pragma unroll
                for (int j = 0; j < 4; ++j) acc[i][j] = 0.0f;

            #pragma unroll 4
            for (int d = 0; d < 64; ++d) {
                float4 xv = *(const float4*)&xsT[d][ty * 4];
                float4 cv = *(const float4*)&csT[tz][d][cx * 4];
                float xr[4] = {xv.x, xv.y, xv.z, xv.w};
                float cc[4] = {cv.x, cv.y, cv.z, cv.w};
                #pragma unroll
                for (int i = 0; i < 4; ++i)
                    #pragma unroll
                    for (int j = 0; j < 4; ++j)
                        acc[i][j] = __fmaf_rn(xr[i], cc[j], acc[i][j]);
            }
            #pragma unroll
            for (int j = 0; j < 4; ++j) {
                int k = st * 256 + tz * 64 + cx * 4 + j;
                float sck = sc[k];
                #pragma unroll
                for (int i = 0; i < 4; ++i) {
                    float tt = __fadd_rn(sxl[ty * 4 + i], sck);
                    float u  = __fmul_rn(2.0f, acc[i][j]);
                    float s  = __fsub_rn(tt, u);
                    if (s < bv[i] || (s == bv[i] && k < bi[i])) { bv[i] = s; bi[i] = k; }
                }
            }
        }

        #pragma unroll
        for (int i = 0; i < 4; ++i) { redv[ty*4+i][tz*16+cx] = bv[i]; redi[ty*4+i][tz*16+cx] = bi[i]; }
        __syncthreads();
        if (tid < 16) {
            float bvv = redv[tid][0]; int bii = redi[tid][0];
            #pragma unroll 8
            for (int i = 1; i < 64; ++i) {
                float v = redv[tid][i]; int k = redi[tid][i];
                if (v < bvv || (v == bvv && k < bii)) { bvv = v; bii = k; }
            }
            idxbuf[rowids[tid]] = bii;
        }
        __syncthreads();
    }
}

// ---------- finalize + loss (unchanged, PASS-verified) ----------
__global__ __launch_bounds__(256) void finalize_rows(
    const float* __restrict__ x, const float* __restrict__ cb,
    const int* __restrict__ idxbuf,
    float* __restrict__ out_q, float* __restrict__ out_i,
    double* __restrict__ partials, int N)
{
    __shared__ double wsum[4];
    int wid = threadIdx.x >> 6, lane = threadIdx.x & 63;
    int n = blockIdx.x * 4 + wid;

    int idx = idxbuf[n];
    float q  = cb[(size_t)idx * D + lane];
    float xv = x[(size_t)n * D + lane];
    out_q[(size_t)n * D + lane] = q;

    double diff = (double)xv - (double)q;
    double s = diff * diff;
    #pragma unroll
    for (int off = 32; off > 0; off >>= 1) s += __shfl_down(s, off, 64);
    if (lane == 0) { wsum[wid] = s; out_i[n] = (float)idx; }
    __syncthreads();
    if (threadIdx.x == 0) partials[blockIdx.x] = (wsum[0] + wsum[1]) + (wsum[2] + wsum[3]);
}

__global__ __launch_bounds__(256) void loss_kernel(const double* __restrict__ partials,
                                                   int nP, float* __restrict__ out_loss,
                                                   double invND)
{
    __shared__ double red[256];
    double s = 0.0;
    for (int i = threadIdx.x; i < nP; i += 256) s += partials[i];
    red[threadIdx.x] = s;
    __syncthreads();
    #pragma unroll
    for (int step = 128; step > 0; step >>= 1) {
        if ((int)threadIdx.x < step) red[threadIdx.x] += red[threadIdx.x + step];
        __syncthreads();
    }
    if (threadIdx.x == 0) {
        double m = red[0] * invND;
        out_loss[0] = (float)(0.25 * m + m);
    }
}

extern "C" void kernel_launch(void* const* d_in, const int* in_sizes, int n_in,
                              void* d_out, int out_size, void* d_ws, size_t ws_size,
                              hipStream_t stream)
{
    const float* x  = (const float*)d_in[0];
    const float* cb = (const float*)d_in[1];
    const int N = in_sizes[0] / D;   // 65536
    const int K = in_sizes[1] / D;   // 4096

    float* out      = (float*)d_out;
    float* out_q    = out;
    float* out_i    = out + (size_t)N * D;
    float* out_loss = out_i + N;

    char* ws = (char*)d_ws;
    bf16x8* cbf      = (bf16x8*)ws;                         // 1 MB
    size_t off = (size_t)(K / 16) * 4 * 64 * sizeof(bf16x8);
    float*  sx       = (float*)(ws + off);  off += (size_t)N * 4;
    float*  sc       = (float*)(ws + off);  off += (size_t)K * 4;
    int*    idxbuf   = (int*)(ws + off);    off += (size_t)N * 4;
    int*    amb_rows = (int*)(ws + off);    off += (size_t)N * 4;
    double* partials = (double*)(ws + off); off += (size_t)(N / 4) * 8;
    int*    amb_cnt  = (int*)(ws + off);

    hipMemsetAsync(amb_cnt, 0, sizeof(int), stream);
    rowsumsq_kernel<<<(N + 255) / 256, 256, 0, stream>>>(x, sx, N);
    rowsumsq_kernel<<<(K + 255) / 256, 256, 0, stream>>>(cb, sc, K);
    pack_cb2<<<K / 16, 256, 0, stream>>>(cb, cbf);
    phase1_kernel<<<N / 128, 256, 0, stream>>>(x, sx, sc, cbf, idxbuf, amb_cnt, amb_rows);
    exact_scan<<<512, 256, 0, stream>>>(x, cb, sx, sc, amb_cnt, amb_rows, idxbuf);
    finalize_rows<<<N / 4, 256, 0, stream>>>(x, cb, idxbuf, out_q, out_i, partials, N);
    loss_kernel<<<1, 256, 0, stream>>>(partials, N / 4, out_loss,
                                       1.0 / ((double)N * (double)D));
}

// Round 7
// 279.052 us; speedup vs baseline: 92.3324x; 1.0863x over previous
//
#include <hip/hip_runtime.h>

// VQ quantizer: N=65536 rows (D=64) vs K=4096 codes. d_out = FLOAT32
// [x_quantized N*D][indices N][loss 1].
//
// Round-7: phase1 made barrier-free. B-fragments are loaded L2->VGPR per wave
// (register double-buffer, one-phase prefetch), no LDS, no __syncthreads.
// Scoring math is bit-identical to the PASS-proven R5/R6 split-bf16 path:
//   s_a = fma(-2, dot_mfma, fl(sx+sc)), dot = xh*ch + xh*cl + xl*ch (6 MFMA)
//   top-2 (m1,i1,m2) per row; gap > MARG_A + sx*MARG_B  ==> winner proven;
//   else exact f32-chain rescan (exact_scan).

#define D  64
#define NT 256          // K/16 code tiles
#define PH 128          // phases = 2 tiles each

typedef unsigned short u16;
typedef short bf16x8 __attribute__((ext_vector_type(8)));
typedef float f32x4  __attribute__((ext_vector_type(4)));

__device__ __forceinline__ u16 f32_to_bf16_raw(float f) {
    union { float f; unsigned u; } v; v.f = f;
    unsigned u = v.u;
    u += 0x7FFFu + ((u >> 16) & 1u);   // RNE
    return (u16)(u >> 16);
}
__device__ __forceinline__ float bf16_raw_to_f32(u16 h) {
    union { unsigned u; float f; } v; v.u = ((unsigned)h) << 16;
    return v.f;
}
__device__ __forceinline__ f32x4 mfma16(bf16x8 a, bf16x8 b, f32x4 c) {
    return __builtin_amdgcn_mfma_f32_16x16x32_bf16(a, b, c, 0, 0, 0);
}

// ---------- numpy-exact row sum of squares (pairwise n=64), proven R3 ----------
__device__ __forceinline__ float np_pairwise_sumsq_64(const float* p) {
    float r[8];
    #pragma unroll
    for (int j = 0; j < 8; ++j) r[j] = __fmul_rn(p[j], p[j]);
    #pragma unroll
    for (int i = 8; i < 64; i += 8) {
        #pragma unroll
        for (int j = 0; j < 8; ++j)
            r[j] = __fadd_rn(r[j], __fmul_rn(p[i + j], p[i + j]));
    }
    float t0 = __fadd_rn(r[0], r[1]);
    float t1 = __fadd_rn(r[2], r[3]);
    float t2 = __fadd_rn(r[4], r[5]);
    float t3 = __fadd_rn(r[6], r[7]);
    return __fadd_rn(__fadd_rn(t0, t1), __fadd_rn(t2, t3));
}

// ---------- fused prep: rowsumsq(x) [256 blk] | rowsumsq(cb) [16 blk] | pack [256 blk]
__global__ __launch_bounds__(256) void prep_kernel(const float* __restrict__ x,
                                                   const float* __restrict__ cb,
                                                   float* __restrict__ sx,
                                                   float* __restrict__ sc,
                                                   bf16x8* __restrict__ cbf) {
    int b = blockIdx.x;
    if (b < 272) {
        // row sum-of-squares: blocks 0..255 -> x rows, 256..271 -> cb rows
        const float* a = (b < 256) ? x : cb;
        float* o = (b < 256) ? sx : sc;
        int r0 = (b < 256) ? b * 256 : (b - 256) * 256;
        int r = r0 + threadIdx.x;
        float buf[64];
        const float4* p = (const float4*)(a + (size_t)r * D);
        #pragma unroll
        for (int i = 0; i < 16; ++i) {
            float4 v = p[i];
            buf[4*i] = v.x; buf[4*i+1] = v.y; buf[4*i+2] = v.z; buf[4*i+3] = v.w;
        }
        o[r] = np_pairwise_sumsq_64(buf);
    } else {
        // pack codebook tile t: head/tail bf16 B-fragments (layout proven R5)
        int t = b - 272;
        int tid = threadIdx.x;
        int lane = tid & 63;
        int ks = (tid >> 6) & 1;
        int hl = tid >> 7;
        int code = t * 16 + (lane & 15);
        int g = lane >> 4;
        bf16x8 v;
        #pragma unroll
        for (int j = 0; j < 8; ++j) {
            int d = ks * 32 + g * 4 + (j & 3) + 16 * (j >> 2);
            float val = cb[(size_t)code * D + d];
            u16 h = f32_to_bf16_raw(val);
            if (hl) {
                float resid = val - bf16_raw_to_f32(h);   // exact (Sterbenz)
                h = f32_to_bf16_raw(resid);
            }
            v[j] = (short)h;
        }
        cbf[((size_t)t * 4 + hl * 2 + ks) * 64 + lane] = v;
    }
}

// ---------- phase 1: split-bf16 MFMA top-2 scan, reg-staged, barrier-free ----------
#define MARG_A 8.0e-6f
#define MARG_B 5.0e-7f

// load one phase (tiles 2p, 2p+1) of B-fragments + sc values into registers
#define LOADPH(B, SCP, p) do {                                              \
    const bf16x8* _b = cbf + (size_t)(p) * 512 + lane;                      \
    B##0 = _b[0];   B##1 = _b[64];  B##2 = _b[128]; B##3 = _b[192];         \
    B##4 = _b[256]; B##5 = _b[320]; B##6 = _b[384]; B##7 = _b[448];         \
    SCP##0 = sc[(2*(p)) * 16 + r];  SCP##1 = sc[(2*(p)+1) * 16 + r];        \
} while (0)

// compute one tile given 4 B-frags; accumulation order identical to R5/R6
#define TILE(b0h, b1h, b0l, b1l, sck, t) do {                               \
    f32x4 accA = {0.f, 0.f, 0.f, 0.f};                                      \
    f32x4 accB = {0.f, 0.f, 0.f, 0.f};                                      \
    accA = mfma16(A0h, b0h, accA);  accB = mfma16(B_0h, b0h, accB);         \
    accA = mfma16(A1h, b1h, accA);  accB = mfma16(B_1h, b1h, accB);         \
    accA = mfma16(A0h, b0l, accA);  accB = mfma16(B_0h, b0l, accB);         \
    accA = mfma16(A1h, b1l, accA);  accB = mfma16(B_1h, b1l, accB);         \
    accA = mfma16(A0l, b0h, accA);  accB = mfma16(B_0l, b0h, accB);         \
    accA = mfma16(A1l, b1h, accA);  accB = mfma16(B_1l, b1h, accB);         \
    int kc = (t) * 16 + r;                                                  \
    _Pragma("unroll")                                                       \
    for (int q = 0; q < 4; ++q) {                                           \
        float s = __fmaf_rn(-2.0f, accA[q], __fadd_rn(sxr[q], sck));        \
        m2[q] = fminf(m2[q], fmaxf(m1[q], s));                              \
        bool lt = s < m1[q];                                                \
        i1[q] = lt ? kc : i1[q];                                            \
        m1[q] = fminf(m1[q], s);                                            \
    }                                                                       \
    _Pragma("unroll")                                                       \
    for (int q = 0; q < 4; ++q) {                                           \
        float s = __fmaf_rn(-2.0f, accB[q], __fadd_rn(sxr[4+q], sck));      \
        m2[4+q] = fminf(m2[4+q], fmaxf(m1[4+q], s));                        \
        bool lt = s < m1[4+q];                                              \
        i1[4+q] = lt ? kc : i1[4+q];                                        \
        m1[4+q] = fminf(m1[4+q], s);                                        \
    }                                                                       \
} while (0)

#define PHASE(B, SCP, p) do {                                               \
    TILE(B##0, B##1, B##2, B##3, SCP##0, 2*(p));                            \
    TILE(B##4, B##5, B##6, B##7, SCP##1, 2*(p)+1);                          \
} while (0)

__global__ __launch_bounds__(256, 2) void phase1_kernel(
    const float* __restrict__ x, const float* __restrict__ sx,
    const float* __restrict__ sc, const bf16x8* __restrict__ cbf,
    int* __restrict__ idxbuf, int* __restrict__ amb_cnt, int* __restrict__ amb_rows)
{
    const int tid  = threadIdx.x;
    const int w    = tid >> 6;
    const int lane = tid & 63;
    const int r = lane & 15, g = lane >> 4;
    const int rowA = blockIdx.x * 128 + w * 32 + r;
    const int rowB = rowA + 16;

    // A fragments (head+tail), identical to R5/R6
    bf16x8 A0h, A1h, A0l, A1l, B_0h, B_1h, B_0l, B_1l;
    {
        const float* xr = x + (size_t)rowA * D;
        float e0[8], e1[8];
        float4 f0 = *(const float4*)(xr + g * 4);
        float4 f1 = *(const float4*)(xr + 16 + g * 4);
        float4 f2 = *(const float4*)(xr + 32 + g * 4);
        float4 f3 = *(const float4*)(xr + 48 + g * 4);
        e0[0]=f0.x;e0[1]=f0.y;e0[2]=f0.z;e0[3]=f0.w; e0[4]=f1.x;e0[5]=f1.y;e0[6]=f1.z;e0[7]=f1.w;
        e1[0]=f2.x;e1[1]=f2.y;e1[2]=f2.z;e1[3]=f2.w; e1[4]=f3.x;e1[5]=f3.y;e1[6]=f3.z;e1[7]=f3.w;
        #pragma unroll
        for (int j = 0; j < 8; ++j) {
            u16 h0 = f32_to_bf16_raw(e0[j]);
            A0h[j] = (short)h0; A0l[j] = (short)f32_to_bf16_raw(e0[j] - bf16_raw_to_f32(h0));
            u16 h1 = f32_to_bf16_raw(e1[j]);
            A1h[j] = (short)h1; A1l[j] = (short)f32_to_bf16_raw(e1[j] - bf16_raw_to_f32(h1));
        }
    }
    {
        const float* xr = x + (size_t)rowB * D;
        float e0[8], e1[8];
        float4 f0 = *(const float4*)(xr + g * 4);
        float4 f1 = *(const float4*)(xr + 16 + g * 4);
        float4 f2 = *(const float4*)(xr + 32 + g * 4);
        float4 f3 = *(const float4*)(xr + 48 + g * 4);
        e0[0]=f0.x;e0[1]=f0.y;e0[2]=f0.z;e0[3]=f0.w; e0[4]=f1.x;e0[5]=f1.y;e0[6]=f1.z;e0[7]=f1.w;
        e1[0]=f2.x;e1[1]=f2.y;e1[2]=f2.z;e1[3]=f2.w; e1[4]=f3.x;e1[5]=f3.y;e1[6]=f3.z;e1[7]=f3.w;
        #pragma unroll
        for (int j = 0; j < 8; ++j) {
            u16 h0 = f32_to_bf16_raw(e0[j]);
            B_0h[j] = (short)h0; B_0l[j] = (short)f32_to_bf16_raw(e0[j] - bf16_raw_to_f32(h0));
            u16 h1 = f32_to_bf16_raw(e1[j]);
            B_1h[j] = (short)h1; B_1l[j] = (short)f32_to_bf16_raw(e1[j] - bf16_raw_to_f32(h1));
        }
    }

    float sxr[8], m1[8], m2[8];
    int   i1[8];
    #pragma unroll
    for (int u = 0; u < 8; ++u) {
        int orow = blockIdx.x * 128 + w * 32 + (u >> 2) * 16 + g * 4 + (u & 3);
        sxr[u] = sx[orow];
        m1[u] = 3.4e38f; m2[u] = 3.4e38f; i1[u] = 0;
    }

    // register double-buffer over phases, one-phase prefetch distance
    bf16x8 PA0, PA1, PA2, PA3, PA4, PA5, PA6, PA7;
    bf16x8 PB0, PB1, PB2, PB3, PB4, PB5, PB6, PB7;
    float  sA0, sA1, sB0, sB1;

    LOADPH(PA, sA, 0);
    LOADPH(PB, sB, 1);
    #pragma unroll 1
    for (int p = 0; p < PH - 2; p += 2) {
        PHASE(PA, sA, p);
        LOADPH(PA, sA, p + 2);
        PHASE(PB, sB, p + 1);
        LOADPH(PB, sB, p + 3);
    }
    PHASE(PA, sA, PH - 2);
    PHASE(PB, sB, PH - 1);

    // merge top-2 across the 16 code-lanes (same g group) — identical to R5/R6
    #pragma unroll
    for (int u = 0; u < 8; ++u) {
        #pragma unroll
        for (int mm = 1; mm < 16; mm <<= 1) {
            float om1 = __shfl_xor(m1[u], mm, 64);
            float om2 = __shfl_xor(m2[u], mm, 64);
            int   oi1 = __shfl_xor(i1[u], mm, 64);
            float nm2 = fminf(fmaxf(m1[u], om1), fminf(m2[u], om2));
            i1[u] = (om1 < m1[u]) ? oi1 : i1[u];
            m1[u] = fminf(m1[u], om1);
            m2[u] = nm2;
        }
    }
    if (r == 0) {
        #pragma unroll
        for (int u = 0; u < 8; ++u) {
            int orow = blockIdx.x * 128 + w * 32 + (u >> 2) * 16 + g * 4 + (u & 3);
            idxbuf[orow] = i1[u];
            float marg = __fmaf_rn(sxr[u], MARG_B, MARG_A);
            if (m2[u] - m1[u] <= marg) {
                int slot = atomicAdd(amb_cnt, 1);
                amb_rows[slot] = orow;
            }
        }
    }
}

// ---------- exact rescan of ambiguous rows (reference-exact f32), proven R5 ----------
__global__ __launch_bounds__(256) void exact_scan(
    const float* __restrict__ x, const float* __restrict__ cb,
    const float* __restrict__ sx, const float* __restrict__ sc,
    const int* __restrict__ amb_cnt, const int* __restrict__ amb_rows,
    int* __restrict__ idxbuf)
{
    __shared__ float csT[4][64][64];   // [tz][d][code]
    __shared__ float xsT[64][16];      // [d][row]
    __shared__ float redv[16][64];
    __shared__ int   redi[16][64];
    __shared__ float sxl[16];
    __shared__ int   rowids[16];

    const int tid = threadIdx.x;
    const int cnt = *amb_cnt;
    const int tz = tid >> 6, ty = (tid >> 4) & 3, cx = tid & 15;

    for (int base = blockIdx.x * 16; base < cnt; base += gridDim.x * 16) {
        if (tid < 16) {
            int i = base + tid;
            int rr = (i < cnt) ? amb_rows[i] : amb_rows[base];
            rowids[tid] = rr;
            sxl[tid] = sx[rr];
        }
        __syncthreads();
        {
            int rr = rowids[tid >> 4];
            int dg = tid & 15;
            float4 v = *(const float4*)(x + (size_t)rr * D + dg * 4);
            xsT[dg*4+0][tid>>4] = v.x; xsT[dg*4+1][tid>>4] = v.y;
            xsT[dg*4+2][tid>>4] = v.z; xsT[dg*4+3][tid>>4] = v.w;
        }

        float bv[4]; int bi[4];
        #pragma unroll
        for (int i = 0; i < 4; ++i) { bv[i] = 3.4e38f; bi[i] = 0x7fffffff; }

        for (int st = 0; st < 16; ++st) {
            __syncthreads();
            {
                int code = st * 256 + tid;
                const float4* src = (const float4*)(cb + (size_t)code * D);
                #pragma unroll
                for (int dd = 0; dd < 16; ++dd) {
                    float4 v = src[dd];
                    csT[tid>>6][dd*4+0][tid&63] = v.x; csT[tid>>6][dd*4+1][tid&63] = v.y;
                    csT[tid>>6][dd*4+2][tid&63] = v.z; csT[tid>>6][dd*4+3][tid&63] = v.w;
                }
            }
            __syncthreads();

            float acc[4][4];
            #pragma unroll
            for (int i = 0; i < 4; ++i)
                #pragma unroll
                for (int j = 0; j < 4; ++j) acc[i][j] = 0.0f;

            #pragma unroll 4
            for (int d = 0; d < 64; ++d) {
                float4 xv = *(const float4*)&xsT[d][ty * 4];
                float4 cv = *(const float4*)&csT[tz][d][cx * 4];
                float xr[4] = {xv.x, xv.y, xv.z, xv.w};
                float cc[4] = {cv.x, cv.y, cv.z, cv.w};
                #pragma unroll
                for (int i = 0; i < 4; ++i)
                    #pragma unroll
                    for (int j = 0; j < 4; ++j)
                        acc[i][j] = __fmaf_rn(xr[i], cc[j], acc[i][j]);
            }
            #pragma unroll
            for (int j = 0; j < 4; ++j) {
                int k = st * 256 + tz * 64 + cx * 4 + j;
                float sck = sc[k];
                #pragma unroll
                for (int i = 0; i < 4; ++i) {
                    float tt = __fadd_rn(sxl[ty * 4 + i], sck);
                    float u  = __fmul_rn(2.0f, acc[i][j]);
                    float s  = __fsub_rn(tt, u);
                    if (s < bv[i] || (s == bv[i] && k < bi[i])) { bv[i] = s; bi[i] = k; }
                }
            }
        }

        #pragma unroll
        for (int i = 0; i < 4; ++i) { redv[ty*4+i][tz*16+cx] = bv[i]; redi[ty*4+i][tz*16+cx] = bi[i]; }
        __syncthreads();
        if (tid < 16) {
            float bvv = redv[tid][0]; int bii = redi[tid][0];
            #pragma unroll 8
            for (int i = 1; i < 64; ++i) {
                float v = redv[tid][i]; int k = redi[tid][i];
                if (v < bvv || (v == bvv && k < bii)) { bvv = v; bii = k; }
            }
            idxbuf[rowids[tid]] = bii;
        }
        __syncthreads();
    }
}

// ---------- finalize + loss (unchanged, PASS-verified) ----------
__global__ __launch_bounds__(256) void finalize_rows(
    const float* __restrict__ x, const float* __restrict__ cb,
    const int* __restrict__ idxbuf,
    float* __restrict__ out_q, float* __restrict__ out_i,
    double* __restrict__ partials, int N)
{
    __shared__ double wsum[4];
    int wid = threadIdx.x >> 6, lane = threadIdx.x & 63;
    int n = blockIdx.x * 4 + wid;

    int idx = idxbuf[n];
    float q  = cb[(size_t)idx * D + lane];
    float xv = x[(size_t)n * D + lane];
    out_q[(size_t)n * D + lane] = q;

    double diff = (double)xv - (double)q;
    double s = diff * diff;
    #pragma unroll
    for (int off = 32; off > 0; off >>= 1) s += __shfl_down(s, off, 64);
    if (lane == 0) { wsum[wid] = s; out_i[n] = (float)idx; }
    __syncthreads();
    if (threadIdx.x == 0) partials[blockIdx.x] = (wsum[0] + wsum[1]) + (wsum[2] + wsum[3]);
}

__global__ __launch_bounds__(256) void loss_kernel(const double* __restrict__ partials,
                                                   int nP, float* __restrict__ out_loss,
                                                   double invND)
{
    __shared__ double red[256];
    double s = 0.0;
    for (int i = threadIdx.x; i < nP; i += 256) s += partials[i];
    red[threadIdx.x] = s;
    __syncthreads();
    #pragma unroll
    for (int step = 128; step > 0; step >>= 1) {
        if ((int)threadIdx.x < step) red[threadIdx.x] += red[threadIdx.x + step];
        __syncthreads();
    }
    if (threadIdx.x == 0) {
        double m = red[0] * invND;
        out_loss[0] = (float)(0.25 * m + m);
    }
}

extern "C" void kernel_launch(void* const* d_in, const int* in_sizes, int n_in,
                              void* d_out, int out_size, void* d_ws, size_t ws_size,
                              hipStream_t stream)
{
    const float* x  = (const float*)d_in[0];
    const float* cb = (const float*)d_in[1];
    const int N = in_sizes[0] / D;   // 65536
    const int K = in_sizes[1] / D;   // 4096

    float* out      = (float*)d_out;
    float* out_q    = out;
    float* out_i    = out + (size_t)N * D;
    float* out_loss = out_i + N;

    char* ws = (char*)d_ws;
    bf16x8* cbf      = (bf16x8*)ws;                         // 1 MB
    size_t off = (size_t)(K / 16) * 4 * 64 * sizeof(bf16x8);
    float*  sx       = (float*)(ws + off);  off += (size_t)N * 4;
    float*  sc       = (float*)(ws + off);  off += (size_t)K * 4;
    int*    idxbuf   = (int*)(ws + off);    off += (size_t)N * 4;
    int*    amb_rows = (int*)(ws + off);    off += (size_t)N * 4;
    double* partials = (double*)(ws + off); off += (size_t)(N / 4) * 8;
    int*    amb_cnt  = (int*)(ws + off);

    hipMemsetAsync(amb_cnt, 0, sizeof(int), stream);
    prep_kernel<<<272 + K / 16, 256, 0, stream>>>(x, cb, sx, sc, cbf);
    phase1_kernel<<<N / 128, 256, 0, stream>>>(x, sx, sc, cbf, idxbuf, amb_cnt, amb_rows);
    exact_scan<<<512, 256, 0, stream>>>(x, cb, sx, sc, amb_cnt, amb_rows, idxbuf);
    finalize_rows<<<N / 4, 256, 0, stream>>>(x, cb, idxbuf, out_q, out_i, partials, N);
    loss_kernel<<<1, 256, 0, stream>>>(partials, N / 4, out_loss,
                                       1.0 / ((double)N * (double)D));
}

// Round 8
// 265.319 us; speedup vs baseline: 97.1114x; 1.0518x over previous
//
#include <hip/hip_runtime.h>

// VQ quantizer: N=65536 rows (D=64) vs K=4096 codes. d_out = FLOAT32
// [x_quantized N*D][indices N][loss 1].
//
// Round-8: phase1 restructured for pinned pipelining + halved L2 traffic:
//  - wave-private LDS rings (depth 3 x 4KB) fed by global_load_lds (no dest
//    reg => compiler can't collapse the prefetch), counted vmcnt, no barriers
//    in the main loop.
//  - split-K wave pairs: each wave = 64 rows x 128 tiles; halves B traffic.
//    Pair merge via LDS + one barrier; exact ties -> gap 0 -> ambiguous.
//  - scoring math bit-identical to PASS-proven R5/R6/R7 split-bf16 path.

#define D  64
#define NT 256          // K/16 code tiles

typedef unsigned short u16;
typedef short bf16x8 __attribute__((ext_vector_type(8)));
typedef float f32x4  __attribute__((ext_vector_type(4)));

#define VMWAIT(n) asm volatile("s_waitcnt vmcnt(" #n ")" ::: "memory")

__device__ __forceinline__ u16 f32_to_bf16_raw(float f) {
    union { float f; unsigned u; } v; v.f = f;
    unsigned u = v.u;
    u += 0x7FFFu + ((u >> 16) & 1u);   // RNE
    return (u16)(u >> 16);
}
__device__ __forceinline__ float bf16_raw_to_f32(u16 h) {
    union { unsigned u; float f; } v; v.u = ((unsigned)h) << 16;
    return v.f;
}
__device__ __forceinline__ f32x4 mfma16(bf16x8 a, bf16x8 b, f32x4 c) {
    return __builtin_amdgcn_mfma_f32_16x16x32_bf16(a, b, c, 0, 0, 0);
}

// ---------- numpy-exact row sum of squares (pairwise n=64), proven R3 ----------
__device__ __forceinline__ float np_pairwise_sumsq_64(const float* p) {
    float r[8];
    #pragma unroll
    for (int j = 0; j < 8; ++j) r[j] = __fmul_rn(p[j], p[j]);
    #pragma unroll
    for (int i = 8; i < 64; i += 8) {
        #pragma unroll
        for (int j = 0; j < 8; ++j)
            r[j] = __fadd_rn(r[j], __fmul_rn(p[i + j], p[i + j]));
    }
    float t0 = __fadd_rn(r[0], r[1]);
    float t1 = __fadd_rn(r[2], r[3]);
    float t2 = __fadd_rn(r[4], r[5]);
    float t3 = __fadd_rn(r[6], r[7]);
    return __fadd_rn(__fadd_rn(t0, t1), __fadd_rn(t2, t3));
}

// ---------- fused prep: rowsumsq(x|cb) + pack + amb_cnt zeroing ----------
__global__ __launch_bounds__(256) void prep_kernel(const float* __restrict__ x,
                                                   const float* __restrict__ cb,
                                                   float* __restrict__ sx,
                                                   float* __restrict__ sc,
                                                   bf16x8* __restrict__ cbf,
                                                   int* __restrict__ amb_cnt) {
    int b = blockIdx.x;
    if (b == 0 && threadIdx.x == 0) *amb_cnt = 0;
    if (b < 272) {
        const float* a = (b < 256) ? x : cb;
        float* o = (b < 256) ? sx : sc;
        int r0 = (b < 256) ? b * 256 : (b - 256) * 256;
        int r = r0 + threadIdx.x;
        float buf[64];
        const float4* p = (const float4*)(a + (size_t)r * D);
        #pragma unroll
        for (int i = 0; i < 16; ++i) {
            float4 v = p[i];
            buf[4*i] = v.x; buf[4*i+1] = v.y; buf[4*i+2] = v.z; buf[4*i+3] = v.w;
        }
        o[r] = np_pairwise_sumsq_64(buf);
    } else {
        // pack codebook tile t: head/tail bf16 B-fragments (layout proven R5)
        int t = b - 272;
        int tid = threadIdx.x;
        int lane = tid & 63;
        int ks = (tid >> 6) & 1;
        int hl = tid >> 7;
        int code = t * 16 + (lane & 15);
        int g = lane >> 4;
        bf16x8 v;
        #pragma unroll
        for (int j = 0; j < 8; ++j) {
            int d = ks * 32 + g * 4 + (j & 3) + 16 * (j >> 2);
            float val = cb[(size_t)code * D + d];
            u16 h = f32_to_bf16_raw(val);
            if (hl) {
                float resid = val - bf16_raw_to_f32(h);   // exact (Sterbenz)
                h = f32_to_bf16_raw(resid);
            }
            v[j] = (short)h;
        }
        cbf[((size_t)t * 4 + hl * 2 + ks) * 64 + lane] = v;
    }
}

// ---------- phase 1: split-bf16 MFMA top-2, wave-private ring, split-K ----------
#define MARG_A 8.0e-6f
#define MARG_B 5.0e-7f

__global__ __launch_bounds__(256, 2) void phase1_kernel(
    const float* __restrict__ x, const float* __restrict__ sx,
    const float* __restrict__ sc, const bf16x8* __restrict__ cbf,
    int* __restrict__ idxbuf, int* __restrict__ amb_cnt, int* __restrict__ amb_rows)
{
    __shared__ __align__(16) char ring[4][3][4096];  // [wave][buf][bytes]
    __shared__ float scl[4096];                      // sc staged in LDS
    __shared__ float lm1[128][2], lm2[128][2];
    __shared__ int   li1[128][2];

    const int tid  = threadIdx.x;
    const int w    = tid >> 6;
    const int lane = tid & 63;
    const int r = lane & 15, g = lane >> 4;
    const int half = w & 1;           // which 128 code-tiles this wave scans
    const int rowg = w >> 1;          // which 64-row group
    const int wbase = blockIdx.x * 128 + rowg * 64;

    // stage sc into LDS, then one barrier (drains these loads only)
    for (int j = tid; j < 1024; j += 256)
        *(float4*)&scl[j * 4] = *(const float4*)&sc[j * 4];
    __syncthreads();

    // A fragments (head+tail) for 4 row-subtiles (rows wbase + s*16 + r)
    bf16x8 Ah0[4], Ah1[4], Al0[4], Al1[4];
    #pragma unroll
    for (int s = 0; s < 4; ++s) {
        const float* xr = x + (size_t)(wbase + s * 16 + r) * D;
        float e0[8], e1[8];
        float4 f0 = *(const float4*)(xr + g * 4);
        float4 f1 = *(const float4*)(xr + 16 + g * 4);
        float4 f2 = *(const float4*)(xr + 32 + g * 4);
        float4 f3 = *(const float4*)(xr + 48 + g * 4);
        e0[0]=f0.x;e0[1]=f0.y;e0[2]=f0.z;e0[3]=f0.w; e0[4]=f1.x;e0[5]=f1.y;e0[6]=f1.z;e0[7]=f1.w;
        e1[0]=f2.x;e1[1]=f2.y;e1[2]=f2.z;e1[3]=f2.w; e1[4]=f3.x;e1[5]=f3.y;e1[6]=f3.z;e1[7]=f3.w;
        #pragma unroll
        for (int j = 0; j < 8; ++j) {
            u16 h0 = f32_to_bf16_raw(e0[j]);
            Ah0[s][j] = (short)h0;
            Al0[s][j] = (short)f32_to_bf16_raw(e0[j] - bf16_raw_to_f32(h0));
            u16 h1 = f32_to_bf16_raw(e1[j]);
            Ah1[s][j] = (short)h1;
            Al1[s][j] = (short)f32_to_bf16_raw(e1[j] - bf16_raw_to_f32(h1));
        }
    }

    // per-(subtile, q) state; orow(u=s*4+q) = wbase + s*16 + g*4 + q
    float sxr[16], m1[16], m2[16];
    int   i1[16];
    #pragma unroll
    for (int u = 0; u < 16; ++u) {
        sxr[u] = sx[wbase + (u >> 2) * 16 + g * 4 + (u & 3)];
        m1[u] = 3.4e38f; m2[u] = 3.4e38f; i1[u] = 0;
    }

    const int t0 = half * 128;
    char* ringbase = &ring[w][0][0];

    // stage tile t into ring buf: 4 x global_load_lds 16B (no dest regs!)
    auto stage = [&](int t, int buf) {
        const char* src = (const char*)cbf + (size_t)t * 4096 + lane * 16;
        char* dst = ringbase + buf * 4096 + lane * 16;
        #pragma unroll
        for (int i = 0; i < 4; ++i)
            __builtin_amdgcn_global_load_lds(
                (const __attribute__((address_space(1))) unsigned int*)(src + i * 1024),
                (__attribute__((address_space(3))) unsigned int*)(dst + i * 1024),
                16, 0, 0);
    };

    // compute one tile; per-acc MFMA chain order identical to R5/R6/R7
    auto compute = [&](int t, int buf) {
        const bf16x8* bfr = (const bf16x8*)(ringbase + buf * 4096);
        bf16x8 b0h = bfr[0 * 64 + lane];
        bf16x8 b1h = bfr[1 * 64 + lane];
        bf16x8 b0l = bfr[2 * 64 + lane];
        bf16x8 b1l = bfr[3 * 64 + lane];
        float sck = scl[t * 16 + r];
        int   kc  = t * 16 + r;

        f32x4 acc[4];
        __builtin_amdgcn_s_setprio(1);
        #pragma unroll
        for (int s = 0; s < 4; ++s) {
            f32x4 a = {0.f, 0.f, 0.f, 0.f};
            a = mfma16(Ah0[s], b0h, a);
            a = mfma16(Ah1[s], b1h, a);
            a = mfma16(Ah0[s], b0l, a);
            a = mfma16(Ah1[s], b1l, a);
            a = mfma16(Al0[s], b0h, a);
            a = mfma16(Al1[s], b1h, a);
            acc[s] = a;
        }
        __builtin_amdgcn_s_setprio(0);

        #pragma unroll
        for (int s = 0; s < 4; ++s) {
            #pragma unroll
            for (int q = 0; q < 4; ++q) {
                int u = s * 4 + q;
                float sv = __fmaf_rn(-2.0f, acc[s][q], __fadd_rn(sxr[u], sck));
                m2[u] = fminf(m2[u], fmaxf(m1[u], sv));
                bool lt = sv < m1[u];
                i1[u] = lt ? kc : i1[u];
                m1[u] = fminf(m1[u], sv);
            }
        }
    };

    VMWAIT(0);                                   // normalize vm counter
    stage(t0 + 0, 0); stage(t0 + 1, 1); stage(t0 + 2, 2);   // 12 outstanding

    #pragma unroll 1
    for (int i = 0; i < 125; ++i) {
        VMWAIT(8);                               // tile t0+i landed
        compute(t0 + i, i % 3);
        asm volatile("s_waitcnt lgkmcnt(0)" ::: "memory");   // ds_reads retired
        __builtin_amdgcn_sched_barrier(0);       // don't hoist the stage
        stage(t0 + i + 3, i % 3);                // refill just-freed buf
    }
    VMWAIT(8); compute(t0 + 125, 125 % 3);
    VMWAIT(4); compute(t0 + 126, 126 % 3);
    VMWAIT(0); compute(t0 + 127, 127 % 3);

    // merge top-2 across the 16 code-lanes (same g group) — identical logic
    #pragma unroll
    for (int u = 0; u < 16; ++u) {
        #pragma unroll
        for (int mm = 1; mm < 16; mm <<= 1) {
            float om1 = __shfl_xor(m1[u], mm, 64);
            float om2 = __shfl_xor(m2[u], mm, 64);
            int   oi1 = __shfl_xor(i1[u], mm, 64);
            float nm2 = fminf(fmaxf(m1[u], om1), fminf(m2[u], om2));
            i1[u] = (om1 < m1[u]) ? oi1 : i1[u];
            m1[u] = fminf(m1[u], om1);
            m2[u] = nm2;
        }
    }
    if (r == 0) {
        #pragma unroll
        for (int u = 0; u < 16; ++u) {
            int rowin = rowg * 64 + (u >> 2) * 16 + g * 4 + (u & 3);
            lm1[rowin][half] = m1[u];
            lm2[rowin][half] = m2[u];
            li1[rowin][half] = i1[u];
        }
    }
    __syncthreads();

    // cross-half merge: exact top-2 of the union; tie -> lower half (first-min)
    if (tid < 128) {
        float a1 = lm1[tid][0], b1 = lm1[tid][1];
        float a2 = lm2[tid][0], b2 = lm2[tid][1];
        int   ia = li1[tid][0], ib = li1[tid][1];
        float m1f = fminf(a1, b1);
        float m2f = fminf(fmaxf(a1, b1), fminf(a2, b2));
        int   i1f = (b1 < a1) ? ib : ia;
        int orow = blockIdx.x * 128 + tid;
        idxbuf[orow] = i1f;
        float marg = __fmaf_rn(sx[orow], MARG_B, MARG_A);
        if (m2f - m1f <= marg) {
            int slot = atomicAdd(amb_cnt, 1);
            amb_rows[slot] = orow;
        }
    }
}

// ---------- exact rescan of ambiguous rows (reference-exact f32), proven R5 ----------
__global__ __launch_bounds__(256) void exact_scan(
    const float* __restrict__ x, const float* __restrict__ cb,
    const float* __restrict__ sx, const float* __restrict__ sc,
    const int* __restrict__ amb_cnt, const int* __restrict__ amb_rows,
    int* __restrict__ idxbuf)
{
    __shared__ float csT[4][64][64];   // [tz][d][code]
    __shared__ float xsT[64][16];      // [d][row]
    __shared__ float redv[16][64];
    __shared__ int   redi[16][64];
    __shared__ float sxl[16];
    __shared__ int   rowids[16];

    const int tid = threadIdx.x;
    const int cnt = *amb_cnt;
    const int tz = tid >> 6, ty = (tid >> 4) & 3, cx = tid & 15;

    for (int base = blockIdx.x * 16; base < cnt; base += gridDim.x * 16) {
        if (tid < 16) {
            int i = base + tid;
            int rr = (i < cnt) ? amb_rows[i] : amb_rows[base];
            rowids[tid] = rr;
            sxl[tid] = sx[rr];
        }
        __syncthreads();
        {
            int rr = rowids[tid >> 4];
            int dg = tid & 15;
            float4 v = *(const float4*)(x + (size_t)rr * D + dg * 4);
            xsT[dg*4+0][tid>>4] = v.x; xsT[dg*4+1][tid>>4] = v.y;
            xsT[dg*4+2][tid>>4] = v.z; xsT[dg*4+3][tid>>4] = v.w;
        }

        float bv[4]; int bi[4];
        #pragma unroll
        for (int i = 0; i < 4; ++i) { bv[i] = 3.4e38f; bi[i] = 0x7fffffff; }

        for (int st = 0; st < 16; ++st) {
            __syncthreads();
            {
                int code = st * 256 + tid;
                const float4* src = (const float4*)(cb + (size_t)code * D);
                #pragma unroll
                for (int dd = 0; dd < 16; ++dd) {
                    float4 v = src[dd];
                    csT[tid>>6][dd*4+0][tid&63] = v.x; csT[tid>>6][dd*4+1][tid&63] = v.y;
                    csT[tid>>6][dd*4+2][tid&63] = v.z; csT[tid>>6][dd*4+3][tid&63] = v.w;
                }
            }
            __syncthreads();

            float acc[4][4];
            #pragma unroll
            for (int i = 0; i < 4; ++i)
                #pragma unroll
                for (int j = 0; j < 4; ++j) acc[i][j] = 0.0f;

            #pragma unroll 4
            for (int d = 0; d < 64; ++d) {
                float4 xv = *(const float4*)&xsT[d][ty * 4];
                float4 cv = *(const float4*)&csT[tz][d][cx * 4];
                float xr[4] = {xv.x, xv.y, xv.z, xv.w};
                float cc[4] = {cv.x, cv.y, cv.z, cv.w};
                #pragma unroll
                for (int i = 0; i < 4; ++i)
                    #pragma unroll
                    for (int j = 0; j < 4; ++j)
                        acc[i][j] = __fmaf_rn(xr[i], cc[j], acc[i][j]);
            }
            #pragma unroll
            for (int j = 0; j < 4; ++j) {
                int k = st * 256 + tz * 64 + cx * 4 + j;
                float sck = sc[k];
                #pragma unroll
                for (int i = 0; i < 4; ++i) {
                    float tt = __fadd_rn(sxl[ty * 4 + i], sck);
                    float u  = __fmul_rn(2.0f, acc[i][j]);
                    float s  = __fsub_rn(tt, u);
                    if (s < bv[i] || (s == bv[i] && k < bi[i])) { bv[i] = s; bi[i] = k; }
                }
            }
        }

        #pragma unroll
        for (int i = 0; i < 4; ++i) { redv[ty*4+i][tz*16+cx] = bv[i]; redi[ty*4+i][tz*16+cx] = bi[i]; }
        __syncthreads();
        if (tid < 16) {
            float bvv = redv[tid][0]; int bii = redi[tid][0];
            #pragma unroll 8
            for (int i = 1; i < 64; ++i) {
                float v = redv[tid][i]; int k = redi[tid][i];
                if (v < bvv || (v == bvv && k < bii)) { bvv = v; bii = k; }
            }
            idxbuf[rowids[tid]] = bii;
        }
        __syncthreads();
    }
}

// ---------- finalize + loss (unchanged, PASS-verified) ----------
__global__ __launch_bounds__(256) void finalize_rows(
    const float* __restrict__ x, const float* __restrict__ cb,
    const int* __restrict__ idxbuf,
    float* __restrict__ out_q, float* __restrict__ out_i,
    double* __restrict__ partials, int N)
{
    __shared__ double wsum[4];
    int wid = threadIdx.x >> 6, lane = threadIdx.x & 63;
    int n = blockIdx.x * 4 + wid;

    int idx = idxbuf[n];
    float q  = cb[(size_t)idx * D + lane];
    float xv = x[(size_t)n * D + lane];
    out_q[(size_t)n * D + lane] = q;

    double diff = (double)xv - (double)q;
    double s = diff * diff;
    #pragma unroll
    for (int off = 32; off > 0; off >>= 1) s += __shfl_down(s, off, 64);
    if (lane == 0) { wsum[wid] = s; out_i[n] = (float)idx; }
    __syncthreads();
    if (threadIdx.x == 0) partials[blockIdx.x] = (wsum[0] + wsum[1]) + (wsum[2] + wsum[3]);
}

__global__ __launch_bounds__(256) void loss_kernel(const double* __restrict__ partials,
                                                   int nP, float* __restrict__ out_loss,
                                                   double invND)
{
    __shared__ double red[256];
    double s = 0.0;
    for (int i = threadIdx.x; i < nP; i += 256) s += partials[i];
    red[threadIdx.x] = s;
    __syncthreads();
    #pragma unroll
    for (int step = 128; step > 0; step >>= 1) {
        if ((int)threadIdx.x < step) red[threadIdx.x] += red[threadIdx.x + step];
        __syncthreads();
    }
    if (threadIdx.x == 0) {
        double m = red[0] * invND;
        out_loss[0] = (float)(0.25 * m + m);
    }
}

extern "C" void kernel_launch(void* const* d_in, const int* in_sizes, int n_in,
                              void* d_out, int out_size, void* d_ws, size_t ws_size,
                              hipStream_t stream)
{
    const float* x  = (const float*)d_in[0];
    const float* cb = (const float*)d_in[1];
    const int N = in_sizes[0] / D;   // 65536
    const int K = in_sizes[1] / D;   // 4096

    float* out      = (float*)d_out;
    float* out_q    = out;
    float* out_i    = out + (size_t)N * D;
    float* out_loss = out_i + N;

    char* ws = (char*)d_ws;
    bf16x8* cbf      = (bf16x8*)ws;                         // 1 MB
    size_t off = (size_t)(K / 16) * 4 * 64 * sizeof(bf16x8);
    float*  sx       = (float*)(ws + off);  off += (size_t)N * 4;
    float*  sc       = (float*)(ws + off);  off += (size_t)K * 4;
    int*    idxbuf   = (int*)(ws + off);    off += (size_t)N * 4;
    int*    amb_rows = (int*)(ws + off);    off += (size_t)N * 4;
    double* partials = (double*)(ws + off); off += (size_t)(N / 4) * 8;
    int*    amb_cnt  = (int*)(ws + off);

    prep_kernel<<<272 + K / 16, 256, 0, stream>>>(x, cb, sx, sc, cbf, amb_cnt);
    phase1_kernel<<<N / 128, 256, 0, stream>>>(x, sx, sc, cbf, idxbuf, amb_cnt, amb_rows);
    exact_scan<<<512, 256, 0, stream>>>(x, cb, sx, sc, amb_cnt, amb_rows, idxbuf);
    finalize_rows<<<N / 4, 256, 0, stream>>>(x, cb, idxbuf, out_q, out_i, partials, N);
    loss_kernel<<<1, 256, 0, stream>>>(partials, N / 4, out_loss,
                                       1.0 / ((double)N * (double)D));
}

// Round 9
// 244.337 us; speedup vs baseline: 105.4507x; 1.0859x over previous
//
#include <hip/hip_runtime.h>

// VQ quantizer: N=65536 rows (D=64) vs K=4096 codes. d_out = FLOAT32
// [x_quantized N*D][indices N][loss 1].
//
// Round-9: distance-2 software pipeline in phase1:
//   it(t): vmcnt(4) -> ds_read frags(t+2) -> stage(t+4) -> VALU(t) -> MFMA(t+2)
// Three rotating acc sets (P0/P1/P2), 3-buffer wave-private LDS ring, all
// static indices. VALU of tile t overlaps MFMA of tile t+2 (dual-pipe).
// Scoring math bit-identical to PASS-proven R5..R8 split-bf16 path.

#define D  64
#define NT 256          // K/16 code tiles

typedef unsigned short u16;
typedef short bf16x8 __attribute__((ext_vector_type(8)));
typedef float f32x4  __attribute__((ext_vector_type(4)));

#define VMWAIT_(n) asm volatile("s_waitcnt vmcnt(" #n ")" ::: "memory")
#define VMWAIT(n) VMWAIT_(n)

__device__ __forceinline__ u16 f32_to_bf16_raw(float f) {
    union { float f; unsigned u; } v; v.f = f;
    unsigned u = v.u;
    u += 0x7FFFu + ((u >> 16) & 1u);   // RNE
    return (u16)(u >> 16);
}
__device__ __forceinline__ float bf16_raw_to_f32(u16 h) {
    union { unsigned u; float f; } v; v.u = ((unsigned)h) << 16;
    return v.f;
}
__device__ __forceinline__ f32x4 mfma16(bf16x8 a, bf16x8 b, f32x4 c) {
    return __builtin_amdgcn_mfma_f32_16x16x32_bf16(a, b, c, 0, 0, 0);
}

// ---------- numpy-exact row sum of squares (pairwise n=64), proven R3 ----------
__device__ __forceinline__ float np_pairwise_sumsq_64(const float* p) {
    float r[8];
    #pragma unroll
    for (int j = 0; j < 8; ++j) r[j] = __fmul_rn(p[j], p[j]);
    #pragma unroll
    for (int i = 8; i < 64; i += 8) {
        #pragma unroll
        for (int j = 0; j < 8; ++j)
            r[j] = __fadd_rn(r[j], __fmul_rn(p[i + j], p[i + j]));
    }
    float t0 = __fadd_rn(r[0], r[1]);
    float t1 = __fadd_rn(r[2], r[3]);
    float t2 = __fadd_rn(r[4], r[5]);
    float t3 = __fadd_rn(r[6], r[7]);
    return __fadd_rn(__fadd_rn(t0, t1), __fadd_rn(t2, t3));
}

// ---------- fused prep: rowsumsq(x|cb) + pack + amb_cnt zeroing ----------
__global__ __launch_bounds__(256) void prep_kernel(const float* __restrict__ x,
                                                   const float* __restrict__ cb,
                                                   float* __restrict__ sx,
                                                   float* __restrict__ sc,
                                                   bf16x8* __restrict__ cbf,
                                                   int* __restrict__ amb_cnt) {
    int b = blockIdx.x;
    if (b == 0 && threadIdx.x == 0) *amb_cnt = 0;
    if (b < 272) {
        const float* a = (b < 256) ? x : cb;
        float* o = (b < 256) ? sx : sc;
        int r0 = (b < 256) ? b * 256 : (b - 256) * 256;
        int r = r0 + threadIdx.x;
        float buf[64];
        const float4* p = (const float4*)(a + (size_t)r * D);
        #pragma unroll
        for (int i = 0; i < 16; ++i) {
            float4 v = p[i];
            buf[4*i] = v.x; buf[4*i+1] = v.y; buf[4*i+2] = v.z; buf[4*i+3] = v.w;
        }
        o[r] = np_pairwise_sumsq_64(buf);
    } else {
        // pack codebook tile t: head/tail bf16 B-fragments (layout proven R5)
        int t = b - 272;
        int tid = threadIdx.x;
        int lane = tid & 63;
        int ks = (tid >> 6) & 1;
        int hl = tid >> 7;
        int code = t * 16 + (lane & 15);
        int g = lane >> 4;
        bf16x8 v;
        #pragma unroll
        for (int j = 0; j < 8; ++j) {
            int d = ks * 32 + g * 4 + (j & 3) + 16 * (j >> 2);
            float val = cb[(size_t)code * D + d];
            u16 h = f32_to_bf16_raw(val);
            if (hl) {
                float resid = val - bf16_raw_to_f32(h);   // exact (Sterbenz)
                h = f32_to_bf16_raw(resid);
            }
            v[j] = (short)h;
        }
        cbf[((size_t)t * 4 + hl * 2 + ks) * 64 + lane] = v;
    }
}

// ---------- phase 1: split-bf16 MFMA top-2, distance-2 pipeline ----------
#define MARG_A 8.0e-6f
#define MARG_B 5.0e-7f

// stage tile T into ring buffer BUF (4 x 16B-wide global_load_lds, no dest regs)
#define STAGE(T, BUF) do {                                                    \
    const char* _src = (const char*)cbf + (size_t)(T) * 4096 + lane * 16;     \
    char* _dst = ringbase + (BUF) * 4096 + lane * 16;                         \
    __builtin_amdgcn_global_load_lds((const __attribute__((address_space(1))) unsigned int*)(_src),        (__attribute__((address_space(3))) unsigned int*)(_dst),        16, 0, 0); \
    __builtin_amdgcn_global_load_lds((const __attribute__((address_space(1))) unsigned int*)(_src + 1024), (__attribute__((address_space(3))) unsigned int*)(_dst + 1024), 16, 0, 0); \
    __builtin_amdgcn_global_load_lds((const __attribute__((address_space(1))) unsigned int*)(_src + 2048), (__attribute__((address_space(3))) unsigned int*)(_dst + 2048), 16, 0, 0); \
    __builtin_amdgcn_global_load_lds((const __attribute__((address_space(1))) unsigned int*)(_src + 3072), (__attribute__((address_space(3))) unsigned int*)(_dst + 3072), 16, 0, 0); \
} while (0)

// read tile T's B-fragments from ring buffer BUF + its sc value into SCK
#define DSREAD(T, BUF, SCK) do {                                              \
    const bf16x8* _bfr = (const bf16x8*)(ringbase + (BUF) * 4096);            \
    Fb0h = _bfr[lane]; Fb1h = _bfr[64 + lane];                                \
    Fb0l = _bfr[128 + lane]; Fb1l = _bfr[192 + lane];                         \
    SCK = scl[(T) * 16 + r];                                                  \
} while (0)

// MFMA cluster for current F-frags into acc set P (chain order identical R5..R8)
#define MFMAC(P) do {                                                         \
    _Pragma("unroll")                                                         \
    for (int s = 0; s < 4; ++s) {                                             \
        f32x4 _a = {0.f, 0.f, 0.f, 0.f};                                      \
        _a = mfma16(Ah0[s], Fb0h, _a);                                        \
        _a = mfma16(Ah1[s], Fb1h, _a);                                        \
        _a = mfma16(Ah0[s], Fb0l, _a);                                        \
        _a = mfma16(Ah1[s], Fb1l, _a);                                        \
        _a = mfma16(Al0[s], Fb0h, _a);                                        \
        _a = mfma16(Al1[s], Fb1h, _a);                                        \
        P[s] = _a;                                                            \
    }                                                                         \
} while (0)

// score top-2 update for tile T from acc set P (math identical R5..R8)
#define VALUU(P, SCK, T) do {                                                 \
    int _kc = (T) * 16 + r;                                                   \
    _Pragma("unroll")                                                         \
    for (int s = 0; s < 4; ++s) {                                             \
        _Pragma("unroll")                                                     \
        for (int q = 0; q < 4; ++q) {                                         \
            int u = s * 4 + q;                                                \
            float sv = __fmaf_rn(-2.0f, P[s][q], __fadd_rn(sxr[u], SCK));     \
            m2[u] = fminf(m2[u], fmaxf(m1[u], sv));                           \
            bool lt = sv < m1[u];                                             \
            i1[u] = lt ? _kc : i1[u];                                         \
            m1[u] = fminf(m1[u], sv);                                         \
        }                                                                     \
    }                                                                         \
} while (0)

// full iteration: wait(t+2) | dsread(t+2) | stage(t+4) | valu(t) | mfma(t+2)
#define ITF(I, BR, BS, PA, PB, SA, SB) do {                                   \
    VMWAIT(4);                                                                \
    DSREAD(t0 + (I) + 2, BR, SB);                                             \
    STAGE(t0 + (I) + 4, BS);                                                  \
    VALUU(PA, SA, t0 + (I));                                                  \
    MFMAC(PB);                                                                \
} while (0)
// tail iteration without stage, custom wait count
#define ITN(I, BR, PA, PB, SA, SB, WN) do {                                   \
    VMWAIT(WN);                                                               \
    DSREAD(t0 + (I) + 2, BR, SB);                                             \
    VALUU(PA, SA, t0 + (I));                                                  \
    MFMAC(PB);                                                                \
} while (0)
#define ITV(I, PA, SA) do { VALUU(PA, SA, t0 + (I)); } while (0)

__global__ __launch_bounds__(256, 2) void phase1_kernel(
    const float* __restrict__ x, const float* __restrict__ sx,
    const float* __restrict__ sc, const bf16x8* __restrict__ cbf,
    int* __restrict__ idxbuf, int* __restrict__ amb_cnt, int* __restrict__ amb_rows)
{
    __shared__ __align__(16) char ring[4][3][4096];  // [wave][buf][bytes]
    __shared__ float scl[4096];                      // sc staged in LDS
    __shared__ float lm1[128][2], lm2[128][2];
    __shared__ int   li1[128][2];

    const int tid  = threadIdx.x;
    const int w    = tid >> 6;
    const int lane = tid & 63;
    const int r = lane & 15, g = lane >> 4;
    const int half = w & 1;           // which 128 code-tiles this wave scans
    const int rowg = w >> 1;          // which 64-row group
    const int wbase = blockIdx.x * 128 + rowg * 64;

    // stage sc into LDS, then one barrier
    for (int j = tid; j < 1024; j += 256)
        *(float4*)&scl[j * 4] = *(const float4*)&sc[j * 4];
    __syncthreads();

    // A fragments (head+tail) for 4 row-subtiles (rows wbase + s*16 + r)
    bf16x8 Ah0[4], Ah1[4], Al0[4], Al1[4];
    #pragma unroll
    for (int s = 0; s < 4; ++s) {
        const float* xr = x + (size_t)(wbase + s * 16 + r) * D;
        float e0[8], e1[8];
        float4 f0 = *(const float4*)(xr + g * 4);
        float4 f1 = *(const float4*)(xr + 16 + g * 4);
        float4 f2 = *(const float4*)(xr + 32 + g * 4);
        float4 f3 = *(const float4*)(xr + 48 + g * 4);
        e0[0]=f0.x;e0[1]=f0.y;e0[2]=f0.z;e0[3]=f0.w; e0[4]=f1.x;e0[5]=f1.y;e0[6]=f1.z;e0[7]=f1.w;
        e1[0]=f2.x;e1[1]=f2.y;e1[2]=f2.z;e1[3]=f2.w; e1[4]=f3.x;e1[5]=f3.y;e1[6]=f3.z;e1[7]=f3.w;
        #pragma unroll
        for (int j = 0; j < 8; ++j) {
            u16 h0 = f32_to_bf16_raw(e0[j]);
            Ah0[s][j] = (short)h0;
            Al0[s][j] = (short)f32_to_bf16_raw(e0[j] - bf16_raw_to_f32(h0));
            u16 h1 = f32_to_bf16_raw(e1[j]);
            Ah1[s][j] = (short)h1;
            Al1[s][j] = (short)f32_to_bf16_raw(e1[j] - bf16_raw_to_f32(h1));
        }
    }

    // per-(subtile, q) state; orow(u=s*4+q) = wbase + s*16 + g*4 + q
    float sxr[16], m1[16], m2[16];
    int   i1[16];
    #pragma unroll
    for (int u = 0; u < 16; ++u) {
        sxr[u] = sx[wbase + (u >> 2) * 16 + g * 4 + (u & 3)];
        m1[u] = 3.4e38f; m2[u] = 3.4e38f; i1[u] = 0;
    }

    const int t0 = half * 128;
    char* ringbase = &ring[w][0][0];

    bf16x8 Fb0h, Fb1h, Fb0l, Fb1l;
    f32x4  P0[4], P1[4], P2[4];
    float  sck0, sck1, sck2;

    // prologue
    VMWAIT(0);                                   // normalize vm counter
    STAGE(t0 + 0, 0); STAGE(t0 + 1, 1);          // out = 8
    VMWAIT(4); DSREAD(t0 + 0, 0, sck0); STAGE(t0 + 2, 2); MFMAC(P0);   // out 8
    VMWAIT(4); DSREAD(t0 + 1, 1, sck1); STAGE(t0 + 3, 0); MFMAC(P1);   // out 8

    // main pipeline: its 0..119 (all with stage, tiles t+4 <= 123)
    #pragma unroll 1
    for (int i = 0; i < 120; i += 3) {
        ITF(i + 0, 2, 1, P0, P2, sck0, sck2);
        ITF(i + 1, 0, 2, P1, P0, sck1, sck0);
        ITF(i + 2, 1, 0, P2, P1, sck2, sck1);
    }
    // tail
    ITF(120, 2, 1, P0, P2, sck0, sck2);
    ITF(121, 0, 2, P1, P0, sck1, sck0);
    ITF(122, 1, 0, P2, P1, sck2, sck1);
    ITF(123, 2, 1, P0, P2, sck0, sck2);          // stages tile 127
    ITN(124, 0, P1, P0, sck1, sck0, 4);
    ITN(125, 1, P2, P1, sck2, sck1, 0);
    ITV(126, P0, sck0);
    ITV(127, P1, sck1);

    // merge top-2 across the 16 code-lanes (same g group) — identical logic
    #pragma unroll
    for (int u = 0; u < 16; ++u) {
        #pragma unroll
        for (int mm = 1; mm < 16; mm <<= 1) {
            float om1 = __shfl_xor(m1[u], mm, 64);
            float om2 = __shfl_xor(m2[u], mm, 64);
            int   oi1 = __shfl_xor(i1[u], mm, 64);
            float nm2 = fminf(fmaxf(m1[u], om1), fminf(m2[u], om2));
            i1[u] = (om1 < m1[u]) ? oi1 : i1[u];
            m1[u] = fminf(m1[u], om1);
            m2[u] = nm2;
        }
    }
    if (r == 0) {
        #pragma unroll
        for (int u = 0; u < 16; ++u) {
            int rowin = rowg * 64 + (u >> 2) * 16 + g * 4 + (u & 3);
            lm1[rowin][half] = m1[u];
            lm2[rowin][half] = m2[u];
            li1[rowin][half] = i1[u];
        }
    }
    __syncthreads();

    // cross-half merge: exact top-2 of the union; tie -> lower half (first-min)
    if (tid < 128) {
        float a1 = lm1[tid][0], b1 = lm1[tid][1];
        float a2 = lm2[tid][0], b2 = lm2[tid][1];
        int   ia = li1[tid][0], ib = li1[tid][1];
        float m1f = fminf(a1, b1);
        float m2f = fminf(fmaxf(a1, b1), fminf(a2, b2));
        int   i1f = (b1 < a1) ? ib : ia;
        int orow = blockIdx.x * 128 + tid;
        idxbuf[orow] = i1f;
        float marg = __fmaf_rn(sx[orow], MARG_B, MARG_A);
        if (m2f - m1f <= marg) {
            int slot = atomicAdd(amb_cnt, 1);
            amb_rows[slot] = orow;
        }
    }
}

// ---------- exact rescan of ambiguous rows (reference-exact f32), proven R5 ----------
__global__ __launch_bounds__(256) void exact_scan(
    const float* __restrict__ x, const float* __restrict__ cb,
    const float* __restrict__ sx, const float* __restrict__ sc,
    const int* __restrict__ amb_cnt, const int* __restrict__ amb_rows,
    int* __restrict__ idxbuf)
{
    __shared__ float csT[4][64][64];   // [tz][d][code]
    __shared__ float xsT[64][16];      // [d][row]
    __shared__ float redv[16][64];
    __shared__ int   redi[16][64];
    __shared__ float sxl[16];
    __shared__ int   rowids[16];

    const int tid = threadIdx.x;
    const int cnt = *amb_cnt;
    const int tz = tid >> 6, ty = (tid >> 4) & 3, cx = tid & 15;

    for (int base = blockIdx.x * 16; base < cnt; base += gridDim.x * 16) {
        if (tid < 16) {
            int i = base + tid;
            int rr = (i < cnt) ? amb_rows[i] : amb_rows[base];
            rowids[tid] = rr;
            sxl[tid] = sx[rr];
        }
        __syncthreads();
        {
            int rr = rowids[tid >> 4];
            int dg = tid & 15;
            float4 v = *(const float4*)(x + (size_t)rr * D + dg * 4);
            xsT[dg*4+0][tid>>4] = v.x; xsT[dg*4+1][tid>>4] = v.y;
            xsT[dg*4+2][tid>>4] = v.z; xsT[dg*4+3][tid>>4] = v.w;
        }

        float bv[4]; int bi[4];
        #pragma unroll
        for (int i = 0; i < 4; ++i) { bv[i] = 3.4e38f; bi[i] = 0x7fffffff; }

        for (int st = 0; st < 16; ++st) {
            __syncthreads();
            {
                int code = st * 256 + tid;
                const float4* src = (const float4*)(cb + (size_t)code * D);
                #pragma unroll
                for (int dd = 0; dd < 16; ++dd) {
                    float4 v = src[dd];
                    csT[tid>>6][dd*4+0][tid&63] = v.x; csT[tid>>6][dd*4+1][tid&63] = v.y;
                    csT[tid>>6][dd*4+2][tid&63] = v.z; csT[tid>>6][dd*4+3][tid&63] = v.w;
                }
            }
            __syncthreads();

            float acc[4][4];
            #pragma unroll
            for (int i = 0; i < 4; ++i)
                #pragma unroll
                for (int j = 0; j < 4; ++j) acc[i][j] = 0.0f;

            #pragma unroll 4
            for (int d = 0; d < 64; ++d) {
                float4 xv = *(const float4*)&xsT[d][ty * 4];
                float4 cv = *(const float4*)&csT[tz][d][cx * 4];
                float xr[4] = {xv.x, xv.y, xv.z, xv.w};
                float cc[4] = {cv.x, cv.y, cv.z, cv.w};
                #pragma unroll
                for (int i = 0; i < 4; ++i)
                    #pragma unroll
                    for (int j = 0; j < 4; ++j)
                        acc[i][j] = __fmaf_rn(xr[i], cc[j], acc[i][j]);
            }
            #pragma unroll
            for (int j = 0; j < 4; ++j) {
                int k = st * 256 + tz * 64 + cx * 4 + j;
                float sck = sc[k];
                #pragma unroll
                for (int i = 0; i < 4; ++i) {
                    float tt = __fadd_rn(sxl[ty * 4 + i], sck);
                    float u  = __fmul_rn(2.0f, acc[i][j]);
                    float s  = __fsub_rn(tt, u);
                    if (s < bv[i] || (s == bv[i] && k < bi[i])) { bv[i] = s; bi[i] = k; }
                }
            }
        }

        #pragma unroll
        for (int i = 0; i < 4; ++i) { redv[ty*4+i][tz*16+cx] = bv[i]; redi[ty*4+i][tz*16+cx] = bi[i]; }
        __syncthreads();
        if (tid < 16) {
            float bvv = redv[tid][0]; int bii = redi[tid][0];
            #pragma unroll 8
            for (int i = 1; i < 64; ++i) {
                float v = redv[tid][i]; int k = redi[tid][i];
                if (v < bvv || (v == bvv && k < bii)) { bvv = v; bii = k; }
            }
            idxbuf[rowids[tid]] = bii;
        }
        __syncthreads();
    }
}

// ---------- finalize + loss (unchanged, PASS-verified) ----------
__global__ __launch_bounds__(256) void finalize_rows(
    const float* __restrict__ x, const float* __restrict__ cb,
    const int* __restrict__ idxbuf,
    float* __restrict__ out_q, float* __restrict__ out_i,
    double* __restrict__ partials, int N)
{
    __shared__ double wsum[4];
    int wid = threadIdx.x >> 6, lane = threadIdx.x & 63;
    int n = blockIdx.x * 4 + wid;

    int idx = idxbuf[n];
    float q  = cb[(size_t)idx * D + lane];
    float xv = x[(size_t)n * D + lane];
    out_q[(size_t)n * D + lane] = q;

    double diff = (double)xv - (double)q;
    double s = diff * diff;
    #pragma unroll
    for (int off = 32; off > 0; off >>= 1) s += __shfl_down(s, off, 64);
    if (lane == 0) { wsum[wid] = s; out_i[n] = (float)idx; }
    __syncthreads();
    if (threadIdx.x == 0) partials[blockIdx.x] = (wsum[0] + wsum[1]) + (wsum[2] + wsum[3]);
}

__global__ __launch_bounds__(256) void loss_kernel(const double* __restrict__ partials,
                                                   int nP, float* __restrict__ out_loss,
                                                   double invND)
{
    __shared__ double red[256];
    double s = 0.0;
    for (int i = threadIdx.x; i < nP; i += 256) s += partials[i];
    red[threadIdx.x] = s;
    __syncthreads();
    #pragma unroll
    for (int step = 128; step > 0; step >>= 1) {
        if ((int)threadIdx.x < step) red[threadIdx.x] += red[threadIdx.x + step];
        __syncthreads();
    }
    if (threadIdx.x == 0) {
        double m = red[0] * invND;
        out_loss[0] = (float)(0.25 * m + m);
    }
}

extern "C" void kernel_launch(void* const* d_in, const int* in_sizes, int n_in,
                              void* d_out, int out_size, void* d_ws, size_t ws_size,
                              hipStream_t stream)
{
    const float* x  = (const float*)d_in[0];
    const float* cb = (const float*)d_in[1];
    const int N = in_sizes[0] / D;   // 65536
    const int K = in_sizes[1] / D;   // 4096

    float* out      = (float*)d_out;
    float* out_q    = out;
    float* out_i    = out + (size_t)N * D;
    float* out_loss = out_i + N;

    char* ws = (char*)d_ws;
    bf16x8* cbf      = (bf16x8*)ws;                         // 1 MB
    size_t off = (size_t)(K / 16) * 4 * 64 * sizeof(bf16x8);
    float*  sx       = (float*)(ws + off);  off += (size_t)N * 4;
    float*  sc       = (float*)(ws + off);  off += (size_t)K * 4;
    int*    idxbuf   = (int*)(ws + off);    off += (size_t)N * 4;
    int*    amb_rows = (int*)(ws + off);    off += (size_t)N * 4;
    double* partials = (double*)(ws + off); off += (size_t)(N / 4) * 8;
    int*    amb_cnt  = (int*)(ws + off);

    prep_kernel<<<272 + K / 16, 256, 0, stream>>>(x, cb, sx, sc, cbf, amb_cnt);
    phase1_kernel<<<N / 128, 256, 0, stream>>>(x, sx, sc, cbf, idxbuf, amb_cnt, amb_rows);
    exact_scan<<<1024, 256, 0, stream>>>(x, cb, sx, sc, amb_cnt, amb_rows, idxbuf);
    finalize_rows<<<N / 4, 256, 0, stream>>>(x, cb, idxbuf, out_q, out_i, partials, N);
    loss_kernel<<<1, 256, 0, stream>>>(partials, N / 4, out_loss,
                                       1.0 / ((double)N * (double)D));
}